// Round 6
// baseline (3443.284 us; speedup 1.0000x reference)
//
#include <hip/hip_runtime.h>

// Fused 2-layer GRU scan. B=256,T=1024,F=64,U=128.
// R13: single-kernel. R12's wave specialization failed (VGPR starved to 84,
// per-kt LDS streaming exposed latency; reverted). R9 analysis: MfmaUtil(46%)
// + VALUBusy(60%) > 100% active => pipes already co-issue; matrix pipe has
// ~330 idle cyc/step of headroom UNDER the VALU roof. So the xw prepass
// (188us dispatch + 384MB HBM round-trip) buys nothing we can't hide: fold
// the 6 W1 MFMAs/wave/step back in-loop (they fill matrix-pipe shadow), keep
// x(t+1) register-prefetched one step ahead (x is L3-resident). Everything
// else is byte-identical to the proven R9 schedule: 16 blocks x 512 thr
// (8 waves, 1 cg/wave), weights reg-resident, parity-double-buffered LDS h
// tiles, layer2 one step delayed, single lgkmcnt(0)+s_barrier per step.

#define TT 1024
#define FF 64
#define G3 384

typedef __attribute__((ext_vector_type(8))) __bf16 bf16x8;
typedef __attribute__((ext_vector_type(4))) float f32x4;

#define MFMA(a, b, c) __builtin_amdgcn_mfma_f32_16x16x32_bf16((a), (b), (c), 0, 0, 0)

__device__ __forceinline__ float sigf(float x) {
    return __builtin_amdgcn_rcpf(1.0f + __expf(-x));
}

__global__ __launch_bounds__(512)
__attribute__((amdgpu_waves_per_eu(2, 2)))
void gru_mono(
    const float* __restrict__ x,  const float* __restrict__ W1,
    const float* __restrict__ U1, const float* __restrict__ b1,
    const float* __restrict__ W2, const float* __restrict__ U2,
    const float* __restrict__ b2, float* __restrict__ out)
{
    const int tid  = threadIdx.x;
    const int wave = tid >> 6;          // 0..7 — owns unit cols wave*16..+15
    const int lane = tid & 63;
    const int quad = lane >> 4;
    const int lc   = lane & 15;
    const int row0 = blockIdx.x * 16;
    const int u    = wave * 16 + lc;    // owned unit column

    __shared__ __align__(16) __bf16 h1s[2][16][136];
    __shared__ __align__(16) __bf16 h2s[2][16][136];
    for (int i = tid; i < 2 * 16 * 136; i += 512) {
        ((__bf16*)h1s)[i] = (__bf16)0.f;
        ((__bf16*)h2s)[i] = (__bf16)0.f;
    }

    // ---- weights: U1,W2,U2 (K=128) + W1 (K=64) = 42 frags = 168 regs ----
    bf16x8 U1B[3][4], W2B[3][4], U2B[3][4], W1B[3][2];
#pragma unroll
    for (int g = 0; g < 3; g++) {
#pragma unroll
        for (int kt = 0; kt < 4; kt++) {
            bf16x8 a, b, c;
#pragma unroll
            for (int j = 0; j < 8; j++) {
                int k = (kt * 32 + quad * 8 + j) * G3 + g * 128 + u;
                a[j] = (__bf16)U1[k];
                b[j] = (__bf16)W2[k];
                c[j] = (__bf16)U2[k];
            }
            U1B[g][kt] = a; W2B[g][kt] = b; U2B[g][kt] = c;
        }
#pragma unroll
        for (int kt = 0; kt < 2; kt++) {
            bf16x8 a;
#pragma unroll
            for (int j = 0; j < 8; j++)
                a[j] = (__bf16)W1[(kt * 32 + quad * 8 + j) * G3 + g * 128 + u];
            W1B[g][kt] = a;
        }
    }

    // ---- biases, hoisted as loop-invariant broadcast quads (MFMA C-in) ----
    const float c1z  = b1[u] + b1[G3 + u];
    const float c1r  = b1[128 + u] + b1[G3 + 128 + u];
    const float b1ih = b1[256 + u];
    const float b1rh = b1[G3 + 256 + u];
    const float c2z  = b2[u] + b2[G3 + u];
    const float c2r  = b2[128 + u] + b2[G3 + 128 + u];
    const float b2ih = b2[256 + u];
    const float b2rh = b2[G3 + 256 + u];
    const f32x4 c1zq  = {c1z, c1z, c1z, c1z};
    const f32x4 c1rq  = {c1r, c1r, c1r, c1r};
    const f32x4 b1ihq = {b1ih, b1ih, b1ih, b1ih};
    const f32x4 b1rhq = {b1rh, b1rh, b1rh, b1rh};
    const f32x4 c2zq  = {c2z, c2z, c2z, c2z};
    const f32x4 c2rq  = {c2r, c2r, c2r, c2r};
    const f32x4 b2ihq = {b2ih, b2ih, b2ih, b2ih};
    const f32x4 b2rhq = {b2rh, b2rh, b2rh, b2rh};

    // ---- x row base + 1-step-ahead register prefetch (x is L3-resident) ----
    const float* xrow = x + (size_t)(row0 + lc) * (TT * FF) + quad * 8;
    f32x4 xp0 = *(const f32x4*)(xrow);
    f32x4 xp1 = *(const f32x4*)(xrow + 4);
    f32x4 xp2 = *(const f32x4*)(xrow + 32);
    f32x4 xp3 = *(const f32x4*)(xrow + 36);

    float h1c[4] = {0, 0, 0, 0};
    float h2c[4] = {0, 0, 0, 0};
    __syncthreads();

#define MSTEP(T, PAR)                                                          \
    {                                                                          \
        bf16x8 A1[4];                                                          \
        _Pragma("unroll") for (int kt = 0; kt < 4; kt++)                       \
            A1[kt] = *(const bf16x8*)&h1s[PAR ^ 1][lc][kt * 32 + quad * 8];    \
        bf16x8 xa0, xa1;                                                       \
        _Pragma("unroll") for (int j = 0; j < 4; j++) {                        \
            xa0[j] = (__bf16)xp0[j]; xa0[j + 4] = (__bf16)xp1[j];              \
            xa1[j] = (__bf16)xp2[j]; xa1[j + 4] = (__bf16)xp3[j];              \
        }                                                                      \
        if ((T) + 1 < TT) { /* prefetch x(T+1) */                              \
            const float* px = xrow + (size_t)((T) + 1) * FF;                   \
            xp0 = *(const f32x4*)px;                                           \
            xp1 = *(const f32x4*)(px + 4);                                     \
            xp2 = *(const f32x4*)(px + 32);                                    \
            xp3 = *(const f32x4*)(px + 36);                                    \
        }                                                                      \
        f32x4 z1  = MFMA(xa0, W1B[0][0], c1zq);                                \
        z1        = MFMA(xa1, W1B[0][1], z1);                                  \
        f32x4 r1  = MFMA(xa0, W1B[1][0], c1rq);                                \
        r1        = MFMA(xa1, W1B[1][1], r1);                                  \
        f32x4 xh1 = MFMA(xa0, W1B[2][0], b1ihq);                               \
        xh1       = MFMA(xa1, W1B[2][1], xh1);                                 \
        f32x4 rh1 = MFMA(A1[0], U1B[2][0], b1rhq);                             \
        z1        = MFMA(A1[0], U1B[0][0], z1);                                \
        r1        = MFMA(A1[0], U1B[1][0], r1);                                \
        _Pragma("unroll") for (int kt = 1; kt < 4; kt++) {                     \
            z1  = MFMA(A1[kt], U1B[0][kt], z1);                                \
            r1  = MFMA(A1[kt], U1B[1][kt], r1);                                \
            rh1 = MFMA(A1[kt], U1B[2][kt], rh1);                               \
        }                                                                      \
        _Pragma("unroll") for (int i = 0; i < 4; i++) {                        \
            float zf = sigf(z1[i]);                                            \
            float rf = sigf(r1[i]);                                            \
            float hh = fmaxf(xh1[i] + rf * rh1[i], 0.f);                       \
            h1c[i] = fmaf(zf, h1c[i] - hh, hh);                                \
            h1s[PAR][quad * 4 + i][u] = (__bf16)h1c[i];                        \
        }                                                                      \
        f32x4 z2  = MFMA(A1[0], W2B[0][0], c2zq);                              \
        f32x4 r2  = MFMA(A1[0], W2B[1][0], c2rq);                              \
        f32x4 xh2 = MFMA(A1[0], W2B[2][0], b2ihq);                             \
        _Pragma("unroll") for (int kt = 1; kt < 4; kt++) {                     \
            z2  = MFMA(A1[kt], W2B[0][kt], z2);                                \
            r2  = MFMA(A1[kt], W2B[1][kt], r2);                                \
            xh2 = MFMA(A1[kt], W2B[2][kt], xh2);                               \
        }                                                                      \
        f32x4 rh2;                                                             \
        {                                                                      \
            bf16x8 A2 = *(const bf16x8*)&h2s[PAR][lc][quad * 8];               \
            rh2 = MFMA(A2, U2B[2][0], b2rhq);                                  \
            z2  = MFMA(A2, U2B[0][0], z2);                                     \
            r2  = MFMA(A2, U2B[1][0], r2);                                     \
        }                                                                      \
        _Pragma("unroll") for (int kt = 1; kt < 4; kt++) {                     \
            bf16x8 A2 = *(const bf16x8*)&h2s[PAR][lc][kt * 32 + quad * 8];     \
            z2  = MFMA(A2, U2B[0][kt], z2);                                    \
            r2  = MFMA(A2, U2B[1][kt], r2);                                    \
            rh2 = MFMA(A2, U2B[2][kt], rh2);                                   \
        }                                                                      \
        if ((T) > 0) {                                                         \
            _Pragma("unroll") for (int i = 0; i < 4; i++) {                    \
                float zf = sigf(z2[i]);                                        \
                float rf = sigf(r2[i]);                                        \
                float hh = fmaxf(xh2[i] + rf * rh2[i], 0.f);                   \
                h2c[i] = fmaf(zf, h2c[i] - hh, hh);                            \
            }                                                                  \
        }                                                                      \
        _Pragma("unroll") for (int i = 0; i < 4; i++)                          \
            h2s[PAR ^ 1][quad * 4 + i][u] = (__bf16)h2c[i];                    \
        asm volatile("s_waitcnt lgkmcnt(0)\n\ts_barrier" ::: "memory");        \
    }

    for (int t = 0; t < TT; t += 2) {
        MSTEP(t, 0)
        MSTEP(t + 1, 1)
    }
#undef MSTEP

    {   // epilogue: h2(TT-1) from h1(TT-1)=h1s[1] and h2(TT-2)=h2s[0]
        f32x4 z2 = c2zq, r2 = c2rq, xh2 = b2ihq, rh2 = b2rhq;
#pragma unroll
        for (int kt = 0; kt < 4; kt++) {
            bf16x8 a1 = *(const bf16x8*)&h1s[1][lc][kt * 32 + quad * 8];
            bf16x8 a2 = *(const bf16x8*)&h2s[0][lc][kt * 32 + quad * 8];
            z2  = MFMA(a1, W2B[0][kt], z2);
            r2  = MFMA(a1, W2B[1][kt], r2);
            xh2 = MFMA(a1, W2B[2][kt], xh2);
            z2  = MFMA(a2, U2B[0][kt], z2);
            r2  = MFMA(a2, U2B[1][kt], r2);
            rh2 = MFMA(a2, U2B[2][kt], rh2);
        }
#pragma unroll
        for (int i = 0; i < 4; i++) {
            float zf = sigf(z2[i]);
            float rf = sigf(r2[i]);
            float hh = fmaxf(xh2[i] + rf * rh2[i], 0.f);
            h2c[i] = fmaf(zf, h2c[i] - hh, hh);
        }
    }

    // out = [x = h2(T-1), state1 = h1(T-1), state2 = h2(T-1)]
#pragma unroll
    for (int i = 0; i < 4; i++) {
        int r = row0 + quad * 4 + i;
        out[(size_t)r * 128 + u]         = h2c[i];
        out[32768 + (size_t)r * 128 + u] = h1c[i];
        out[65536 + (size_t)r * 128 + u] = h2c[i];
    }
}

extern "C" void kernel_launch(void* const* d_in, const int* in_sizes, int n_in,
                              void* d_out, int out_size, void* d_ws, size_t ws_size,
                              hipStream_t stream) {
    const float* x  = (const float*)d_in[0];
    const float* W1 = (const float*)d_in[1];
    const float* U1 = (const float*)d_in[2];
    const float* b1 = (const float*)d_in[3];
    const float* W2 = (const float*)d_in[4];
    const float* U2 = (const float*)d_in[5];
    const float* b2 = (const float*)d_in[6];
    float* out = (float*)d_out;

    gru_mono<<<dim3(16), dim3(512), 0, stream>>>(
        x, W1, U1, b1, W2, U2, b2, out);
}

// Round 7
// 1205.042 us; speedup vs baseline: 2.8574x; 2.8574x over previous
//
#include <hip/hip_runtime.h>

// Fused 2-layer GRU scan. B=256,T=1024,F=64,U=128.
// R14: persist kernel = R9 verbatim (best measured: 1058us, passed). R13's
// in-loop W1 (42 frags = 168 regs) overflowed the 128-AGPR half of the
// 2-wave/SIMD unified file -> scratch spills -> 3.4ms. Confirmed: weight set
// must stay <=36 frags for this structure; W1 lives in the prepass.
// R14 change is prepass-only: each wave now processes 8 timesteps (grid
// 16x32, 512 blocks instead of 4096), holding the 8 x-tiles in registers
// (64 VGPRs, statically indexed) and loading each W1 fragment ONCE per 8
// steps instead of once per step. 8x fewer W1 scalar gathers + 8x fewer
// block launches; output bytes identical to the verified prepass.

#define TT 1024
#define FF 64
#define G3 384
#define XW_BYTES (1024ull * 384 * 256 * 2)

typedef __attribute__((ext_vector_type(8))) __bf16 bf16x8;
typedef __attribute__((ext_vector_type(4))) float f32x4;
typedef __attribute__((ext_vector_type(4))) int i32x4;

#define MFMA(a, b, c) __builtin_amdgcn_mfma_f32_16x16x32_bf16((a), (b), (c), 0, 0, 0)
#define BCAST(w) __builtin_bit_cast(bf16x8, w)

__device__ __forceinline__ float sigf(float x) {
    return __builtin_amdgcn_rcpf(1.0f + __expf(-x));
}

__device__ __forceinline__ f32x4 unpackv(uint2 v) {
    f32x4 o;
    o[0] = __uint_as_float(v.x << 16);
    o[1] = __uint_as_float(v.x & 0xFFFF0000u);
    o[2] = __uint_as_float(v.y << 16);
    o[3] = __uint_as_float(v.y & 0xFFFF0000u);
    return o;
}

// ---- prepass: ws uint2 index = ((t*16+rb)*3+g)*512 + cg*64 + lane ---------
// slot holds batch rows quad*4..+3, unit col cg*16+lc, bf16x4 packed.
// Gates z,r carry BOTH biases; gate h only the input bias (b_rh separate).
// Each wave handles 8 timesteps: t = blockIdx.y*32 + wave + 4*tt.
__global__ __launch_bounds__(256)
void xw_prepass(
    const float* __restrict__ x, const float* __restrict__ W1,
    const float* __restrict__ b1, unsigned short* __restrict__ ws)
{
    const int tid = threadIdx.x, wave = tid >> 6, lane = tid & 63;
    const int quad = lane >> 4, lc = lane & 15;
    const int rb = blockIdx.x;              // row block (16 rows)
    const int t0 = blockIdx.y * 32 + wave;  // + 4*tt, tt = 0..7

    // ---- x tiles for 8 timesteps -> 16 bf16x8 frags (64 VGPRs, static) ----
    bf16x8 xa0[8], xa1[8];
#pragma unroll
    for (int tt = 0; tt < 8; tt++) {
        const float* px =
            x + ((size_t)(rb * 16 + lc) * TT + (t0 + 4 * tt)) * FF + quad * 8;
        f32x4 u0 = *(const f32x4*)px;
        f32x4 u1 = *(const f32x4*)(px + 4);
        f32x4 u2 = *(const f32x4*)(px + 32);
        f32x4 u3 = *(const f32x4*)(px + 36);
#pragma unroll
        for (int j = 0; j < 4; j++) {
            xa0[tt][j] = (__bf16)u0[j]; xa0[tt][j + 4] = (__bf16)u1[j];
            xa1[tt][j] = (__bf16)u2[j]; xa1[tt][j + 4] = (__bf16)u3[j];
        }
    }

    for (int nt = 0; nt < 24; nt++) {
        const int g  = nt >> 3;
        const int cg = nt & 7;
        const int uc = cg * 16 + lc;
        float bi = b1[g * 128 + uc];
        if (g < 2) bi += b1[G3 + g * 128 + uc];   // fold recurrent bias (z,r)
        bf16x8 w0, w1v;                           // loaded ONCE per 8 steps
#pragma unroll
        for (int j = 0; j < 8; j++) {
            w0[j]  = (__bf16)W1[(quad * 8 + j) * G3 + g * 128 + uc];
            w1v[j] = (__bf16)W1[(32 + quad * 8 + j) * G3 + g * 128 + uc];
        }
#pragma unroll
        for (int tt = 0; tt < 8; tt++) {
            f32x4 acc = {bi, bi, bi, bi};
            acc = MFMA(xa0[tt], w0, acc);
            acc = MFMA(xa1[tt], w1v, acc);
            unsigned int s0 = __builtin_bit_cast(unsigned short, (__bf16)acc[0]);
            unsigned int s1 = __builtin_bit_cast(unsigned short, (__bf16)acc[1]);
            unsigned int s2 = __builtin_bit_cast(unsigned short, (__bf16)acc[2]);
            unsigned int s3 = __builtin_bit_cast(unsigned short, (__bf16)acc[3]);
            uint2 st;
            st.x = s0 | (s1 << 16);
            st.y = s2 | (s3 << 16);
            uint2* wq = (uint2*)ws
                        + ((size_t)(t0 + 4 * tt) * 16 + rb) * 1536 + lane;
            wq[(size_t)(g * 8 + cg) * 64] = st;   // 512B contiguous per wave
        }
    }
}

// ---- persistent scan kernel (R9 verbatim; measured 1058us) ----------------
template <bool PRE>
__global__ __launch_bounds__(512)
__attribute__((amdgpu_waves_per_eu(2, 2)))
void gru_persist(
    const float* __restrict__ x,  const float* __restrict__ W1,
    const float* __restrict__ U1, const float* __restrict__ b1,
    const float* __restrict__ W2, const float* __restrict__ U2,
    const float* __restrict__ b2, const unsigned short* __restrict__ xw,
    float* __restrict__ out)
{
    const int tid  = threadIdx.x;
    const int wave = tid >> 6;          // 0..7 — owns unit cols wave*16..+15
    const int lane = tid & 63;
    const int quad = lane >> 4;
    const int lc   = lane & 15;
    const int row0 = blockIdx.x * 16;
    const int u    = wave * 16 + lc;    // owned unit column

    __shared__ __align__(16) __bf16 h1s[2][16][136];
    __shared__ __align__(16) __bf16 h2s[2][16][136];
    for (int i = tid; i < 2 * 16 * 136; i += 512) {
        ((__bf16*)h1s)[i] = (__bf16)0.f;
        ((__bf16*)h2s)[i] = (__bf16)0.f;
    }

    // ---- weight B-frags: 1 column group/wave -> 36 frags = 144 regs ----
    i32x4 U1B[3][4], W2B[3][4], U2B[3][4];
    i32x4 W1B[3][2];                    // !PRE only (dead in PRE)
#pragma unroll
    for (int g = 0; g < 3; g++) {
#pragma unroll
        for (int kt = 0; kt < 4; kt++) {
            bf16x8 a, b, c;
#pragma unroll
            for (int j = 0; j < 8; j++) {
                int k = (kt * 32 + quad * 8 + j) * G3 + g * 128 + u;
                a[j] = (__bf16)U1[k];
                b[j] = (__bf16)W2[k];
                c[j] = (__bf16)U2[k];
            }
            U1B[g][kt] = __builtin_bit_cast(i32x4, a);
            W2B[g][kt] = __builtin_bit_cast(i32x4, b);
            U2B[g][kt] = __builtin_bit_cast(i32x4, c);
        }
        if constexpr (!PRE) {
#pragma unroll
            for (int kt = 0; kt < 2; kt++) {
                bf16x8 a;
#pragma unroll
                for (int j = 0; j < 8; j++)
                    a[j] = (__bf16)W1[(kt * 32 + quad * 8 + j) * G3 + g * 128 + u];
                W1B[g][kt] = __builtin_bit_cast(i32x4, a);
            }
        }
    }
#pragma unroll
    for (int g = 0; g < 3; g++) {
#pragma unroll
        for (int kt = 0; kt < 4; kt++)
            asm volatile("" : "+v"(U1B[g][kt]), "+v"(W2B[g][kt]), "+v"(U2B[g][kt]));
        if constexpr (!PRE) {
#pragma unroll
            for (int kt = 0; kt < 2; kt++)
                asm volatile("" : "+v"(W1B[g][kt]));
        }
    }

    // ---- biases (zero here; honored) ----
    float c1z  = b1[u] + b1[G3 + u];               // used only when !PRE
    float c1r  = b1[128 + u] + b1[G3 + 128 + u];   // used only when !PRE
    float b1ih = b1[256 + u];                      // used only when !PRE
    float b1rh = b1[G3 + 256 + u];
    float c2z  = b2[u] + b2[G3 + u];
    float c2r  = b2[128 + u] + b2[G3 + 128 + u];
    float b2ih = b2[256 + u];
    float b2rh = b2[G3 + 256 + u];

    // ---- xw base: uint2 index = ((t*16+rb)*3+g)*512 + wave*64 + lane ----
    const uint2* xqb = (const uint2*)xw + (size_t)blockIdx.x * 1536
                       + wave * 64 + lane;
    uint2 xwv[3];                       // 1-step-ahead prefetch buffer
    if constexpr (PRE) {
#pragma unroll
        for (int g = 0; g < 3; g++)
            xwv[g] = xqb[(size_t)g * 512];
    }
    const float* xrow = x + (size_t)(row0 + lc) * (TT * FF) + quad * 8;

    float h1c[4] = {0, 0, 0, 0};
    float h2c[4] = {0, 0, 0, 0};

    __syncthreads();

#define STEP(T, PAR)                                                           \
    {                                                                          \
        bf16x8 A1[4];                                                          \
        _Pragma("unroll") for (int kt = 0; kt < 4; kt++)                       \
            A1[kt] = *(const bf16x8*)&h1s[PAR ^ 1][lc][kt * 32 + quad * 8];    \
        f32x4 z1, r1, rh1, xh1;                                                \
        if constexpr (PRE) {                                                   \
            z1  = unpackv(xwv[0]);  /* xz incl. both biases */                 \
            r1  = unpackv(xwv[1]);                                             \
            xh1 = unpackv(xwv[2]);  /* xh incl. input bias */                  \
            rh1 = (f32x4){b1rh, b1rh, b1rh, b1rh};                             \
            if ((T) + 1 < TT) {                                                \
                _Pragma("unroll") for (int g = 0; g < 3; g++)                  \
                    xwv[g] = xqb[(size_t)((T) + 1) * 24576 + g * 512];         \
            }                                                                  \
        } else {                                                               \
            const float* px = xrow + (size_t)(T) * FF;                         \
            f32x4 u0 = *(const f32x4*)px;                                      \
            f32x4 u1 = *(const f32x4*)(px + 4);                                \
            f32x4 u2 = *(const f32x4*)(px + 32);                               \
            f32x4 u3 = *(const f32x4*)(px + 36);                               \
            bf16x8 xa0, xa1;                                                   \
            _Pragma("unroll") for (int j = 0; j < 4; j++) {                    \
                xa0[j] = (__bf16)u0[j]; xa0[j + 4] = (__bf16)u1[j];            \
                xa1[j] = (__bf16)u2[j]; xa1[j + 4] = (__bf16)u3[j];            \
            }                                                                  \
            z1  = (f32x4){c1z, c1z, c1z, c1z};                                 \
            r1  = (f32x4){c1r, c1r, c1r, c1r};                                 \
            rh1 = (f32x4){b1rh, b1rh, b1rh, b1rh};                             \
            xh1 = (f32x4){b1ih, b1ih, b1ih, b1ih};                             \
            z1  = MFMA(xa0, BCAST(W1B[0][0]), z1);                             \
            z1  = MFMA(xa1, BCAST(W1B[0][1]), z1);                             \
            r1  = MFMA(xa0, BCAST(W1B[1][0]), r1);                             \
            r1  = MFMA(xa1, BCAST(W1B[1][1]), r1);                             \
            xh1 = MFMA(xa0, BCAST(W1B[2][0]), xh1);                            \
            xh1 = MFMA(xa1, BCAST(W1B[2][1]), xh1);                            \
        }                                                                      \
        _Pragma("unroll") for (int kt = 0; kt < 4; kt++) {                     \
            z1  = MFMA(A1[kt], BCAST(U1B[0][kt]), z1);                         \
            r1  = MFMA(A1[kt], BCAST(U1B[1][kt]), r1);                         \
            rh1 = MFMA(A1[kt], BCAST(U1B[2][kt]), rh1);                        \
        }                                                                      \
        _Pragma("unroll") for (int i = 0; i < 4; i++) {                        \
            float zf = sigf(z1[i]);                                            \
            float rf = sigf(r1[i]);                                            \
            float hh = fmaxf(xh1[i] + rf * rh1[i], 0.f);                       \
            h1c[i] = fmaf(zf, h1c[i] - hh, hh);                                \
            h1s[PAR][quad * 4 + i][u] = (__bf16)h1c[i];                        \
        }                                                                      \
        f32x4 z2  = (f32x4){c2z, c2z, c2z, c2z};                               \
        f32x4 r2  = (f32x4){c2r, c2r, c2r, c2r};                               \
        f32x4 xh2 = (f32x4){b2ih, b2ih, b2ih, b2ih};                           \
        f32x4 rh2 = (f32x4){b2rh, b2rh, b2rh, b2rh};                           \
        _Pragma("unroll") for (int kt = 0; kt < 4; kt++) {                     \
            z2  = MFMA(A1[kt], BCAST(W2B[0][kt]), z2);                         \
            r2  = MFMA(A1[kt], BCAST(W2B[1][kt]), r2);                         \
            xh2 = MFMA(A1[kt], BCAST(W2B[2][kt]), xh2);                        \
        }                                                                      \
        _Pragma("unroll") for (int kt = 0; kt < 4; kt++) {                     \
            bf16x8 A2 = *(const bf16x8*)&h2s[PAR][lc][kt * 32 + quad * 8];     \
            z2  = MFMA(A2, BCAST(U2B[0][kt]), z2);                             \
            r2  = MFMA(A2, BCAST(U2B[1][kt]), r2);                             \
            rh2 = MFMA(A2, BCAST(U2B[2][kt]), rh2);                            \
        }                                                                      \
        if ((T) > 0) {                                                         \
            _Pragma("unroll") for (int i = 0; i < 4; i++) {                    \
                float zf = sigf(z2[i]);                                        \
                float rf = sigf(r2[i]);                                        \
                float hh = fmaxf(xh2[i] + rf * rh2[i], 0.f);                   \
                h2c[i] = fmaf(zf, h2c[i] - hh, hh);                            \
            }                                                                  \
        }                                                                      \
        _Pragma("unroll") for (int i = 0; i < 4; i++)                          \
            h2s[PAR ^ 1][quad * 4 + i][u] = (__bf16)h2c[i];                    \
        asm volatile("s_waitcnt lgkmcnt(0)\n\ts_barrier" ::: "memory");        \
    }

    for (int t = 0; t < TT; t += 2) {
        STEP(t, 0)
        STEP(t + 1, 1)
    }
#undef STEP

    // Epilogue: h2(TT-1) from h1(TT-1) (h1s[1]) and h2(TT-2) (h2s[0])
    {
        f32x4 z2  = (f32x4){c2z, c2z, c2z, c2z};
        f32x4 r2  = (f32x4){c2r, c2r, c2r, c2r};
        f32x4 xh2 = (f32x4){b2ih, b2ih, b2ih, b2ih};
        f32x4 rh2 = (f32x4){b2rh, b2rh, b2rh, b2rh};
#pragma unroll
        for (int kt = 0; kt < 4; kt++) {
            bf16x8 a1 = *(const bf16x8*)&h1s[1][lc][kt * 32 + quad * 8];
            bf16x8 a2 = *(const bf16x8*)&h2s[0][lc][kt * 32 + quad * 8];
            z2  = MFMA(a1, BCAST(W2B[0][kt]), z2);
            r2  = MFMA(a1, BCAST(W2B[1][kt]), r2);
            xh2 = MFMA(a1, BCAST(W2B[2][kt]), xh2);
            z2  = MFMA(a2, BCAST(U2B[0][kt]), z2);
            r2  = MFMA(a2, BCAST(U2B[1][kt]), r2);
            rh2 = MFMA(a2, BCAST(U2B[2][kt]), rh2);
        }
#pragma unroll
        for (int i = 0; i < 4; i++) {
            float zf = sigf(z2[i]);
            float rf = sigf(r2[i]);
            float hh = fmaxf(xh2[i] + rf * rh2[i], 0.f);
            h2c[i] = fmaf(zf, h2c[i] - hh, hh);
        }
    }

    // out = [x = h2(T-1), state1 = h1(T-1), state2 = h2(T-1)]
#pragma unroll
    for (int i = 0; i < 4; i++) {
        int r = row0 + quad * 4 + i;
        out[(size_t)r * 128 + u]         = h2c[i];
        out[32768 + (size_t)r * 128 + u] = h1c[i];
        out[65536 + (size_t)r * 128 + u] = h2c[i];
    }
}

extern "C" void kernel_launch(void* const* d_in, const int* in_sizes, int n_in,
                              void* d_out, int out_size, void* d_ws, size_t ws_size,
                              hipStream_t stream) {
    const float* x  = (const float*)d_in[0];
    const float* W1 = (const float*)d_in[1];
    const float* U1 = (const float*)d_in[2];
    const float* b1 = (const float*)d_in[3];
    const float* W2 = (const float*)d_in[4];
    const float* U2 = (const float*)d_in[5];
    const float* b2 = (const float*)d_in[6];
    float* out = (float*)d_out;

    if (ws_size >= XW_BYTES) {
        unsigned short* ws = (unsigned short*)d_ws;
        xw_prepass<<<dim3(16, 32), dim3(256), 0, stream>>>(x, W1, b1, ws);
        gru_persist<true><<<dim3(16), dim3(512), 0, stream>>>(
            x, W1, U1, b1, W2, U2, b2, ws, out);
    } else {
        gru_persist<false><<<dim3(16), dim3(512), 0, stream>>>(
            x, W1, U1, b1, W2, U2, b2, nullptr, out);
    }
}

// Round 8
// 1123.103 us; speedup vs baseline: 3.0659x; 1.0730x over previous
//
#include <hip/hip_runtime.h>

// Fused 2-layer GRU scan. B=256,T=1024,F=64,U=128.
// R15: layer pipeline, chunked. R11 proved the cross-block protocol correct
// but paid ~10k cyc/step (per-step fence+flag). R15 amortizes sync 64x:
// one kernel, 32 blocks. Blocks 0-15 = layer-1 producers (W1 in-loop, 6+12
// MFMA/wave/step; NO prepass kernel); blocks 16-31 = layer-2 consumers
// (W2+U2, 24 MFMA/wave/step). Producer stores h1(t-1) A-frags (already in
// registers from its own LDS read, lane-coalesced 1KB/kt) to a 64MB ws ring;
// fence+release-flag once per 64 steps. Consumer spin-acquires per chunk
// (16 waits total), prefetches h1 one step ahead within the chunk, and runs
// a straight layer-2 scan (no delay trick, no epilogue). Producer bid rb and
// consumer bid rb+16 land on the same XCD under round-robin -> L2-local
// handoff. Flags zeroed via 1KB hipMemsetAsync. Per-CU per-step work halves
// vs R9's 2480 cyc (VALU-roofed); expect ~startup + 1024 consumer steps.

#define TT 1024
#define FF 64
#define G3 384
#define NB 16
#define CHUNK 64
#define NCH (TT / CHUNK)
#define FLAG_BYTES 1024
#define H1F_BYTES ((size_t)NB * TT * 4096)
#define PIPE_WS (FLAG_BYTES + H1F_BYTES)

typedef __attribute__((ext_vector_type(8))) __bf16 bf16x8;
typedef __attribute__((ext_vector_type(4))) float f32x4;

#define MFMA(a, b, c) __builtin_amdgcn_mfma_f32_16x16x32_bf16((a), (b), (c), 0, 0, 0)

__device__ __forceinline__ float sigf(float x) {
    return __builtin_amdgcn_rcpf(1.0f + __expf(-x));
}

__device__ __forceinline__ void wait_flag(const unsigned int* f) {
    while (__hip_atomic_load(f, __ATOMIC_ACQUIRE, __HIP_MEMORY_SCOPE_AGENT) == 0u)
        __builtin_amdgcn_s_sleep(1);
}

// ---- fused pipeline: blocks 0-15 layer1 producers, 16-31 layer2 consumers -
__global__ __launch_bounds__(512)
__attribute__((amdgpu_waves_per_eu(2, 2)))
void gru_pipe2(
    const float* __restrict__ x,  const float* __restrict__ W1,
    const float* __restrict__ U1, const float* __restrict__ b1,
    const float* __restrict__ W2, const float* __restrict__ U2,
    const float* __restrict__ b2, unsigned char* __restrict__ ws,
    float* __restrict__ out)
{
    const int tid  = threadIdx.x;
    const int wave = tid >> 6;
    const int lane = tid & 63;
    const int quad = lane >> 4;
    const int lc   = lane & 15;
    const int rb   = blockIdx.x & 15;
    const int row0 = rb * 16;
    const int u    = wave * 16 + lc;

    unsigned int* flags = (unsigned int*)ws + rb * NCH;
    unsigned char* h1f  = ws + FLAG_BYTES + (size_t)rb * TT * 4096;

    __shared__ __align__(16) __bf16 hs[2][16][136];
    for (int i = tid; i < 2 * 16 * 136; i += 512)
        ((__bf16*)hs)[i] = (__bf16)0.f;

    if (blockIdx.x < NB) {
        // =================== PRODUCER: layer 1 ===========================
        bf16x8 U1B[3][4], W1B[3][2];      // 18 frags = 72 regs
#pragma unroll
        for (int g = 0; g < 3; g++) {
#pragma unroll
            for (int kt = 0; kt < 4; kt++) {
                bf16x8 a;
#pragma unroll
                for (int j = 0; j < 8; j++)
                    a[j] = (__bf16)U1[(kt * 32 + quad * 8 + j) * G3 + g * 128 + u];
                U1B[g][kt] = a;
            }
#pragma unroll
            for (int kt = 0; kt < 2; kt++) {
                bf16x8 a;
#pragma unroll
                for (int j = 0; j < 8; j++)
                    a[j] = (__bf16)W1[(kt * 32 + quad * 8 + j) * G3 + g * 128 + u];
                W1B[g][kt] = a;
            }
        }
        const float c1z  = b1[u] + b1[G3 + u];
        const float c1r  = b1[128 + u] + b1[G3 + 128 + u];
        const float b1ih = b1[256 + u];
        const float b1rh = b1[G3 + 256 + u];
        const f32x4 c1zq  = {c1z, c1z, c1z, c1z};
        const f32x4 c1rq  = {c1r, c1r, c1r, c1r};
        const f32x4 b1ihq = {b1ih, b1ih, b1ih, b1ih};
        const f32x4 b1rhq = {b1rh, b1rh, b1rh, b1rh};

        const float* xrow = x + (size_t)(row0 + lc) * (TT * FF) + quad * 8;
        f32x4 xp0 = *(const f32x4*)(xrow);
        f32x4 xp1 = *(const f32x4*)(xrow + 4);
        f32x4 xp2 = *(const f32x4*)(xrow + 32);
        f32x4 xp3 = *(const f32x4*)(xrow + 36);

        float h1c[4] = {0, 0, 0, 0};
        __syncthreads();

#define PSTEP(T, PAR)                                                          \
    {                                                                          \
        bf16x8 A1[4];                                                          \
        _Pragma("unroll") for (int kt = 0; kt < 4; kt++)                       \
            A1[kt] = *(const bf16x8*)&hs[PAR ^ 1][lc][kt * 32 + quad * 8];     \
        if ((T) > 0 && wave == 0) { /* publish h1(T-1): A-frag layout */       \
            _Pragma("unroll") for (int kt = 0; kt < 4; kt++)                   \
                *(bf16x8*)(h1f + ((size_t)((T) - 1) * 4 + kt) * 1024           \
                           + lane * 16) = A1[kt];                              \
        }                                                                      \
        bf16x8 xa0, xa1;                                                       \
        _Pragma("unroll") for (int j = 0; j < 4; j++) {                        \
            xa0[j] = (__bf16)xp0[j]; xa0[j + 4] = (__bf16)xp1[j];              \
            xa1[j] = (__bf16)xp2[j]; xa1[j + 4] = (__bf16)xp3[j];              \
        }                                                                      \
        if ((T) + 1 < TT) {                                                    \
            const float* px = xrow + (size_t)((T) + 1) * FF;                   \
            xp0 = *(const f32x4*)px;                                           \
            xp1 = *(const f32x4*)(px + 4);                                     \
            xp2 = *(const f32x4*)(px + 32);                                    \
            xp3 = *(const f32x4*)(px + 36);                                    \
        }                                                                      \
        f32x4 z1  = MFMA(xa0, W1B[0][0], c1zq);                                \
        z1        = MFMA(xa1, W1B[0][1], z1);                                  \
        f32x4 r1  = MFMA(xa0, W1B[1][0], c1rq);                                \
        r1        = MFMA(xa1, W1B[1][1], r1);                                  \
        f32x4 xh1 = MFMA(xa0, W1B[2][0], b1ihq);                               \
        xh1       = MFMA(xa1, W1B[2][1], xh1);                                 \
        f32x4 rh1 = MFMA(A1[0], U1B[2][0], b1rhq);                             \
        z1        = MFMA(A1[0], U1B[0][0], z1);                                \
        r1        = MFMA(A1[0], U1B[1][0], r1);                                \
        _Pragma("unroll") for (int kt = 1; kt < 4; kt++) {                     \
            z1  = MFMA(A1[kt], U1B[0][kt], z1);                                \
            r1  = MFMA(A1[kt], U1B[1][kt], r1);                                \
            rh1 = MFMA(A1[kt], U1B[2][kt], rh1);                               \
        }                                                                      \
        _Pragma("unroll") for (int i = 0; i < 4; i++) {                        \
            float zf = sigf(z1[i]);                                            \
            float rf = sigf(r1[i]);                                            \
            float hh = fmaxf(xh1[i] + rf * rh1[i], 0.f);                       \
            h1c[i] = fmaf(zf, h1c[i] - hh, hh);                                \
            hs[PAR][quad * 4 + i][u] = (__bf16)h1c[i];                         \
        }                                                                      \
        if (wave == 0 && (T) > 0 && (((T) & 63) == 0)) {                       \
            __threadfence(); /* drain this chunk's h1f stores (wave 0) */      \
            if (lane == 0)                                                     \
                __hip_atomic_store(flags + ((T) >> 6) - 1, 1u,                 \
                                   __ATOMIC_RELEASE,                           \
                                   __HIP_MEMORY_SCOPE_AGENT);                  \
        }                                                                      \
        asm volatile("s_waitcnt lgkmcnt(0)\n\ts_barrier" ::: "memory");        \
    }

        for (int t = 0; t < TT; t += 2) {
            PSTEP(t, 0)
            PSTEP(t + 1, 1)
        }
#undef PSTEP

        // epilogue: publish h1(1023) (lives in hs[1]) + final flag
        if (wave == 0) {
#pragma unroll
            for (int kt = 0; kt < 4; kt++) {
                bf16x8 a = *(const bf16x8*)&hs[1][lc][kt * 32 + quad * 8];
                *(bf16x8*)(h1f + ((size_t)(TT - 1) * 4 + kt) * 1024
                           + lane * 16) = a;
            }
            __threadfence();
            if (lane == 0)
                __hip_atomic_store(flags + NCH - 1, 1u, __ATOMIC_RELEASE,
                                   __HIP_MEMORY_SCOPE_AGENT);
        }
        // state1 = h1(1023)
#pragma unroll
        for (int i = 0; i < 4; i++) {
            int r = row0 + quad * 4 + i;
            out[32768 + (size_t)r * 128 + u] = h1c[i];
        }
    } else {
        // =================== CONSUMER: layer 2 ===========================
        bf16x8 W2B[3][4], U2B[3][4];      // 24 frags = 96 regs
#pragma unroll
        for (int g = 0; g < 3; g++)
#pragma unroll
            for (int kt = 0; kt < 4; kt++) {
                bf16x8 b, c;
#pragma unroll
                for (int j = 0; j < 8; j++) {
                    int k = (kt * 32 + quad * 8 + j) * G3 + g * 128 + u;
                    b[j] = (__bf16)W2[k];
                    c[j] = (__bf16)U2[k];
                }
                W2B[g][kt] = b;
                U2B[g][kt] = c;
            }
        const float c2z  = b2[u] + b2[G3 + u];
        const float c2r  = b2[128 + u] + b2[G3 + 128 + u];
        const float b2ih = b2[256 + u];
        const float b2rh = b2[G3 + 256 + u];
        const f32x4 c2zq  = {c2z, c2z, c2z, c2z};
        const f32x4 c2rq  = {c2r, c2r, c2r, c2r};
        const f32x4 b2ihq = {b2ih, b2ih, b2ih, b2ih};
        const f32x4 b2rhq = {b2rh, b2rh, b2rh, b2rh};

        float h2c[4] = {0, 0, 0, 0};
        bf16x8 hAa0, hAa1, hAa2, hAa3, hAb0, hAb1, hAb2, hAb3;
        __syncthreads();

#define CSTEP(T, PAR, C0, C1, C2, C3, N0, N1, N2, N3)                          \
    {                                                                          \
        if ((T) + 1 < tend) { /* prefetch h1(T+1) within chunk */              \
            const unsigned char* sp =                                          \
                h1f + (size_t)((T) + 1) * 4096 + lane * 16;                    \
            N0 = *(const bf16x8*)(sp);                                         \
            N1 = *(const bf16x8*)(sp + 1024);                                  \
            N2 = *(const bf16x8*)(sp + 2048);                                  \
            N3 = *(const bf16x8*)(sp + 3072);                                  \
        }                                                                      \
        f32x4 z2  = MFMA(C0, W2B[0][0], c2zq);                                 \
        f32x4 r2  = MFMA(C0, W2B[1][0], c2rq);                                 \
        f32x4 xh2 = MFMA(C0, W2B[2][0], b2ihq);                                \
        z2  = MFMA(C1, W2B[0][1], z2);                                         \
        r2  = MFMA(C1, W2B[1][1], r2);                                         \
        xh2 = MFMA(C1, W2B[2][1], xh2);                                        \
        z2  = MFMA(C2, W2B[0][2], z2);                                         \
        r2  = MFMA(C2, W2B[1][2], r2);                                         \
        xh2 = MFMA(C2, W2B[2][2], xh2);                                        \
        z2  = MFMA(C3, W2B[0][3], z2);                                         \
        r2  = MFMA(C3, W2B[1][3], r2);                                         \
        xh2 = MFMA(C3, W2B[2][3], xh2);                                        \
        f32x4 rh2;                                                             \
        {                                                                      \
            bf16x8 A2 = *(const bf16x8*)&hs[PAR ^ 1][lc][quad * 8];            \
            rh2 = MFMA(A2, U2B[2][0], b2rhq);                                  \
            z2  = MFMA(A2, U2B[0][0], z2);                                     \
            r2  = MFMA(A2, U2B[1][0], r2);                                     \
        }                                                                      \
        _Pragma("unroll") for (int kt = 1; kt < 4; kt++) {                     \
            bf16x8 A2 = *(const bf16x8*)&hs[PAR ^ 1][lc][kt * 32 + quad * 8];  \
            z2  = MFMA(A2, U2B[0][kt], z2);                                    \
            r2  = MFMA(A2, U2B[1][kt], r2);                                    \
            rh2 = MFMA(A2, U2B[2][kt], rh2);                                   \
        }                                                                      \
        _Pragma("unroll") for (int i = 0; i < 4; i++) {                        \
            float zf = sigf(z2[i]);                                            \
            float rf = sigf(r2[i]);                                            \
            float hh = fmaxf(xh2[i] + rf * rh2[i], 0.f);                       \
            h2c[i] = fmaf(zf, h2c[i] - hh, hh);                                \
            hs[PAR][quad * 4 + i][u] = (__bf16)h2c[i];                         \
        }                                                                      \
        asm volatile("s_waitcnt lgkmcnt(0)\n\ts_barrier" ::: "memory");        \
    }

        for (int c = 0; c < NCH; c++) {
            wait_flag(flags + c);
            const int t0   = c * CHUNK;
            const int tend = t0 + CHUNK;
            {   // blocking load of h1(t0)
                const unsigned char* sp = h1f + (size_t)t0 * 4096 + lane * 16;
                hAa0 = *(const bf16x8*)(sp);
                hAa1 = *(const bf16x8*)(sp + 1024);
                hAa2 = *(const bf16x8*)(sp + 2048);
                hAa3 = *(const bf16x8*)(sp + 3072);
            }
            for (int t = t0; t < tend; t += 2) {
                CSTEP(t, 0, hAa0, hAa1, hAa2, hAa3, hAb0, hAb1, hAb2, hAb3)
                CSTEP(t + 1, 1, hAb0, hAb1, hAb2, hAb3, hAa0, hAa1, hAa2, hAa3)
            }
        }
#undef CSTEP

        // out: x = h2(1023), state2 = h2(1023)  (no delay -> no epilogue)
#pragma unroll
        for (int i = 0; i < 4; i++) {
            int r = row0 + quad * 4 + i;
            out[(size_t)r * 128 + u]         = h2c[i];
            out[65536 + (size_t)r * 128 + u] = h2c[i];
        }
    }
}

// ---- monolithic fallback (ws too small): R13 gru_mono, proven correct -----
__global__ __launch_bounds__(512)
__attribute__((amdgpu_waves_per_eu(2, 2)))
void gru_mono(
    const float* __restrict__ x,  const float* __restrict__ W1,
    const float* __restrict__ U1, const float* __restrict__ b1,
    const float* __restrict__ W2, const float* __restrict__ U2,
    const float* __restrict__ b2, float* __restrict__ out)
{
    const int tid  = threadIdx.x;
    const int wave = tid >> 6;
    const int lane = tid & 63;
    const int quad = lane >> 4;
    const int lc   = lane & 15;
    const int row0 = blockIdx.x * 16;
    const int u    = wave * 16 + lc;

    __shared__ __align__(16) __bf16 h1s[2][16][136];
    __shared__ __align__(16) __bf16 h2s[2][16][136];
    for (int i = tid; i < 2 * 16 * 136; i += 512) {
        ((__bf16*)h1s)[i] = (__bf16)0.f;
        ((__bf16*)h2s)[i] = (__bf16)0.f;
    }

    bf16x8 U1B[3][4], W2B[3][4], U2B[3][4], W1B[3][2];
#pragma unroll
    for (int g = 0; g < 3; g++) {
#pragma unroll
        for (int kt = 0; kt < 4; kt++) {
            bf16x8 a, b, c;
#pragma unroll
            for (int j = 0; j < 8; j++) {
                int k = (kt * 32 + quad * 8 + j) * G3 + g * 128 + u;
                a[j] = (__bf16)U1[k];
                b[j] = (__bf16)W2[k];
                c[j] = (__bf16)U2[k];
            }
            U1B[g][kt] = a; W2B[g][kt] = b; U2B[g][kt] = c;
        }
#pragma unroll
        for (int kt = 0; kt < 2; kt++) {
            bf16x8 a;
#pragma unroll
            for (int j = 0; j < 8; j++)
                a[j] = (__bf16)W1[(kt * 32 + quad * 8 + j) * G3 + g * 128 + u];
            W1B[g][kt] = a;
        }
    }

    const float c1z  = b1[u] + b1[G3 + u];
    const float c1r  = b1[128 + u] + b1[G3 + 128 + u];
    const float b1ih = b1[256 + u];
    const float b1rh = b1[G3 + 256 + u];
    const float c2z  = b2[u] + b2[G3 + u];
    const float c2r  = b2[128 + u] + b2[G3 + 128 + u];
    const float b2ih = b2[256 + u];
    const float b2rh = b2[G3 + 256 + u];
    const f32x4 c1zq  = {c1z, c1z, c1z, c1z};
    const f32x4 c1rq  = {c1r, c1r, c1r, c1r};
    const f32x4 b1ihq = {b1ih, b1ih, b1ih, b1ih};
    const f32x4 b1rhq = {b1rh, b1rh, b1rh, b1rh};
    const f32x4 c2zq  = {c2z, c2z, c2z, c2z};
    const f32x4 c2rq  = {c2r, c2r, c2r, c2r};
    const f32x4 b2ihq = {b2ih, b2ih, b2ih, b2ih};
    const f32x4 b2rhq = {b2rh, b2rh, b2rh, b2rh};

    const float* xrow = x + (size_t)(row0 + lc) * (TT * FF) + quad * 8;
    float h1c[4] = {0, 0, 0, 0};
    float h2c[4] = {0, 0, 0, 0};
    __syncthreads();

#define MSTEP(T, PAR)                                                          \
    {                                                                          \
        bf16x8 A1[4];                                                          \
        _Pragma("unroll") for (int kt = 0; kt < 4; kt++)                       \
            A1[kt] = *(const bf16x8*)&h1s[PAR ^ 1][lc][kt * 32 + quad * 8];    \
        const float* px = xrow + (size_t)(T) * FF;                             \
        f32x4 u0 = *(const f32x4*)px;                                          \
        f32x4 u1 = *(const f32x4*)(px + 4);                                    \
        f32x4 u2 = *(const f32x4*)(px + 32);                                   \
        f32x4 u3 = *(const f32x4*)(px + 36);                                   \
        bf16x8 xa0, xa1;                                                       \
        _Pragma("unroll") for (int j = 0; j < 4; j++) {                        \
            xa0[j] = (__bf16)u0[j]; xa0[j + 4] = (__bf16)u1[j];                \
            xa1[j] = (__bf16)u2[j]; xa1[j + 4] = (__bf16)u3[j];                \
        }                                                                      \
        f32x4 z1  = MFMA(xa0, W1B[0][0], c1zq);                                \
        z1        = MFMA(xa1, W1B[0][1], z1);                                  \
        f32x4 r1  = MFMA(xa0, W1B[1][0], c1rq);                                \
        r1        = MFMA(xa1, W1B[1][1], r1);                                  \
        f32x4 xh1 = MFMA(xa0, W1B[2][0], b1ihq);                               \
        xh1       = MFMA(xa1, W1B[2][1], xh1);                                 \
        f32x4 rh1 = MFMA(A1[0], U1B[2][0], b1rhq);                             \
        z1        = MFMA(A1[0], U1B[0][0], z1);                                \
        r1        = MFMA(A1[0], U1B[1][0], r1);                                \
        _Pragma("unroll") for (int kt = 1; kt < 4; kt++) {                     \
            z1  = MFMA(A1[kt], U1B[0][kt], z1);                                \
            r1  = MFMA(A1[kt], U1B[1][kt], r1);                                \
            rh1 = MFMA(A1[kt], U1B[2][kt], rh1);                               \
        }                                                                      \
        _Pragma("unroll") for (int i = 0; i < 4; i++) {                        \
            float zf = sigf(z1[i]);                                            \
            float rf = sigf(r1[i]);                                            \
            float hh = fmaxf(xh1[i] + rf * rh1[i], 0.f);                       \
            h1c[i] = fmaf(zf, h1c[i] - hh, hh);                                \
            h1s[PAR][quad * 4 + i][u] = (__bf16)h1c[i];                        \
        }                                                                      \
        f32x4 z2  = MFMA(A1[0], W2B[0][0], c2zq);                              \
        f32x4 r2  = MFMA(A1[0], W2B[1][0], c2rq);                              \
        f32x4 xh2 = MFMA(A1[0], W2B[2][0], b2ihq);                             \
        _Pragma("unroll") for (int kt = 1; kt < 4; kt++) {                     \
            z2  = MFMA(A1[kt], W2B[0][kt], z2);                                \
            r2  = MFMA(A1[kt], W2B[1][kt], r2);                                \
            xh2 = MFMA(A1[kt], W2B[2][kt], xh2);                               \
        }                                                                      \
        f32x4 rh2;                                                             \
        {                                                                      \
            bf16x8 A2 = *(const bf16x8*)&h2s[PAR][lc][quad * 8];               \
            rh2 = MFMA(A2, U2B[2][0], b2rhq);                                  \
            z2  = MFMA(A2, U2B[0][0], z2);                                     \
            r2  = MFMA(A2, U2B[1][0], r2);                                     \
        }                                                                      \
        _Pragma("unroll") for (int kt = 1; kt < 4; kt++) {                     \
            bf16x8 A2 = *(const bf16x8*)&h2s[PAR][lc][kt * 32 + quad * 8];     \
            z2  = MFMA(A2, U2B[0][kt], z2);                                    \
            r2  = MFMA(A2, U2B[1][kt], r2);                                    \
            rh2 = MFMA(A2, U2B[2][kt], rh2);                                   \
        }                                                                      \
        if ((T) > 0) {                                                         \
            _Pragma("unroll") for (int i = 0; i < 4; i++) {                    \
                float zf = sigf(z2[i]);                                        \
                float rf = sigf(r2[i]);                                        \
                float hh = fmaxf(xh2[i] + rf * rh2[i], 0.f);                   \
                h2c[i] = fmaf(zf, h2c[i] - hh, hh);                            \
            }                                                                  \
        }                                                                      \
        _Pragma("unroll") for (int i = 0; i < 4; i++)                          \
            h2s[PAR ^ 1][quad * 4 + i][u] = (__bf16)h2c[i];                    \
        asm volatile("s_waitcnt lgkmcnt(0)\n\ts_barrier" ::: "memory");        \
    }

    for (int t = 0; t < TT; t += 2) {
        MSTEP(t, 0)
        MSTEP(t + 1, 1)
    }
#undef MSTEP

    {
        f32x4 z2 = c2zq, r2 = c2rq, xh2 = b2ihq, rh2 = b2rhq;
#pragma unroll
        for (int kt = 0; kt < 4; kt++) {
            bf16x8 a1 = *(const bf16x8*)&h1s[1][lc][kt * 32 + quad * 8];
            bf16x8 a2 = *(const bf16x8*)&h2s[0][lc][kt * 32 + quad * 8];
            z2  = MFMA(a1, W2B[0][kt], z2);
            r2  = MFMA(a1, W2B[1][kt], r2);
            xh2 = MFMA(a1, W2B[2][kt], xh2);
            z2  = MFMA(a2, U2B[0][kt], z2);
            r2  = MFMA(a2, U2B[1][kt], r2);
            rh2 = MFMA(a2, U2B[2][kt], rh2);
        }
#pragma unroll
        for (int i = 0; i < 4; i++) {
            float zf = sigf(z2[i]);
            float rf = sigf(r2[i]);
            float hh = fmaxf(xh2[i] + rf * rh2[i], 0.f);
            h2c[i] = fmaf(zf, h2c[i] - hh, hh);
        }
    }

#pragma unroll
    for (int i = 0; i < 4; i++) {
        int r = row0 + quad * 4 + i;
        out[(size_t)r * 128 + u]         = h2c[i];
        out[32768 + (size_t)r * 128 + u] = h1c[i];
        out[65536 + (size_t)r * 128 + u] = h2c[i];
    }
}

extern "C" void kernel_launch(void* const* d_in, const int* in_sizes, int n_in,
                              void* d_out, int out_size, void* d_ws, size_t ws_size,
                              hipStream_t stream) {
    const float* x  = (const float*)d_in[0];
    const float* W1 = (const float*)d_in[1];
    const float* U1 = (const float*)d_in[2];
    const float* b1 = (const float*)d_in[3];
    const float* W2 = (const float*)d_in[4];
    const float* U2 = (const float*)d_in[5];
    const float* b2 = (const float*)d_in[6];
    float* out = (float*)d_out;

    if (ws_size >= PIPE_WS) {
        hipMemsetAsync(d_ws, 0, FLAG_BYTES, stream);
        gru_pipe2<<<dim3(2 * NB), dim3(512), 0, stream>>>(
            x, W1, U1, b1, W2, U2, b2, (unsigned char*)d_ws, out);
    } else {
        gru_mono<<<dim3(NB), dim3(512), 0, stream>>>(
            x, W1, U1, b1, W2, U2, b2, out);
    }
}

// Round 9
// 1080.366 us; speedup vs baseline: 3.1871x; 1.0396x over previous
//
#include <hip/hip_runtime.h>

// Fused 2-layer GRU scan. B=256,T=1024,F=64,U=128.
// R16: R15 (layer pipeline, 64-step chunked handshake, 1123us) left 44% of
// each step stalled: splitting the layers cut per-step issue work ~2x but
// also cut chain-level ILP -- z2/r2 were 8-deep serial MFMA chains (4 W2 +
// 4 U2 into one accumulator), and with only 6 chains/step the MFMA+LDS
// latency stopped being hidden (R9 had 12+ chains; it ran issue-bound).
// Fixes, same skeleton: (1) split accumulators -- W2-part and U2-part go to
// separate 4-deep chains, one f32x4 add combines (same for producer z1/r1);
// (2) hoist A2/A1 LDS loads ahead of the LDS-independent W-part chains so
// ds latency hides under real work; (3) h1 prefetch distance 1 -> 2 steps
// (same 2 buffers, prefetch T+2 into the buffer being consumed) to cover
// L2-miss latency at the shorter step. Protocol, layout, chunking: R15.

#define TT 1024
#define FF 64
#define G3 384
#define NB 16
#define CHUNK 64
#define NCH (TT / CHUNK)
#define FLAG_BYTES 1024
#define H1F_BYTES ((size_t)NB * TT * 4096)
#define PIPE_WS (FLAG_BYTES + H1F_BYTES)

typedef __attribute__((ext_vector_type(8))) __bf16 bf16x8;
typedef __attribute__((ext_vector_type(4))) float f32x4;

#define MFMA(a, b, c) __builtin_amdgcn_mfma_f32_16x16x32_bf16((a), (b), (c), 0, 0, 0)

__device__ __forceinline__ float sigf(float x) {
    return __builtin_amdgcn_rcpf(1.0f + __expf(-x));
}

__device__ __forceinline__ void wait_flag(const unsigned int* f) {
    while (__hip_atomic_load(f, __ATOMIC_ACQUIRE, __HIP_MEMORY_SCOPE_AGENT) == 0u)
        __builtin_amdgcn_s_sleep(1);
}

// ---- fused pipeline: blocks 0-15 layer1 producers, 16-31 layer2 consumers -
__global__ __launch_bounds__(512)
__attribute__((amdgpu_waves_per_eu(2, 2)))
void gru_pipe2(
    const float* __restrict__ x,  const float* __restrict__ W1,
    const float* __restrict__ U1, const float* __restrict__ b1,
    const float* __restrict__ W2, const float* __restrict__ U2,
    const float* __restrict__ b2, unsigned char* __restrict__ ws,
    float* __restrict__ out)
{
    const int tid  = threadIdx.x;
    const int wave = tid >> 6;
    const int lane = tid & 63;
    const int quad = lane >> 4;
    const int lc   = lane & 15;
    const int rb   = blockIdx.x & 15;
    const int row0 = rb * 16;
    const int u    = wave * 16 + lc;

    unsigned int* flags = (unsigned int*)ws + rb * NCH;
    unsigned char* h1f  = ws + FLAG_BYTES + (size_t)rb * TT * 4096;

    __shared__ __align__(16) __bf16 hs[2][16][136];
    for (int i = tid; i < 2 * 16 * 136; i += 512)
        ((__bf16*)hs)[i] = (__bf16)0.f;

    const f32x4 zeroq = {0.f, 0.f, 0.f, 0.f};

    if (blockIdx.x < NB) {
        // =================== PRODUCER: layer 1 ===========================
        bf16x8 U1B[3][4], W1B[3][2];      // 18 frags = 72 regs
#pragma unroll
        for (int g = 0; g < 3; g++) {
#pragma unroll
            for (int kt = 0; kt < 4; kt++) {
                bf16x8 a;
#pragma unroll
                for (int j = 0; j < 8; j++)
                    a[j] = (__bf16)U1[(kt * 32 + quad * 8 + j) * G3 + g * 128 + u];
                U1B[g][kt] = a;
            }
#pragma unroll
            for (int kt = 0; kt < 2; kt++) {
                bf16x8 a;
#pragma unroll
                for (int j = 0; j < 8; j++)
                    a[j] = (__bf16)W1[(kt * 32 + quad * 8 + j) * G3 + g * 128 + u];
                W1B[kt == 0 ? g : g][kt] = a;   // plain assign
            }
        }
        const float c1z  = b1[u] + b1[G3 + u];
        const float c1r  = b1[128 + u] + b1[G3 + 128 + u];
        const float b1ih = b1[256 + u];
        const float b1rh = b1[G3 + 256 + u];
        const f32x4 c1zq  = {c1z, c1z, c1z, c1z};
        const f32x4 c1rq  = {c1r, c1r, c1r, c1r};
        const f32x4 b1ihq = {b1ih, b1ih, b1ih, b1ih};
        const f32x4 b1rhq = {b1rh, b1rh, b1rh, b1rh};

        const float* xrow = x + (size_t)(row0 + lc) * (TT * FF) + quad * 8;
        f32x4 xp0 = *(const f32x4*)(xrow);
        f32x4 xp1 = *(const f32x4*)(xrow + 4);
        f32x4 xp2 = *(const f32x4*)(xrow + 32);
        f32x4 xp3 = *(const f32x4*)(xrow + 36);

        float h1c[4] = {0, 0, 0, 0};
        __syncthreads();

#define PSTEP(T, PAR)                                                          \
    {                                                                          \
        bf16x8 A1[4];                                                          \
        _Pragma("unroll") for (int kt = 0; kt < 4; kt++)                       \
            A1[kt] = *(const bf16x8*)&hs[PAR ^ 1][lc][kt * 32 + quad * 8];     \
        bf16x8 xa0, xa1;                                                       \
        _Pragma("unroll") for (int j = 0; j < 4; j++) {                        \
            xa0[j] = (__bf16)xp0[j]; xa0[j + 4] = (__bf16)xp1[j];              \
            xa1[j] = (__bf16)xp2[j]; xa1[j + 4] = (__bf16)xp3[j];              \
        }                                                                      \
        if ((T) + 1 < TT) {                                                    \
            const float* px = xrow + (size_t)((T) + 1) * FF;                   \
            xp0 = *(const f32x4*)px;                                           \
            xp1 = *(const f32x4*)(px + 4);                                     \
            xp2 = *(const f32x4*)(px + 32);                                    \
            xp3 = *(const f32x4*)(px + 36);                                    \
        }                                                                      \
        /* W1-part chains (independent of A1 -> hide ds latency) */            \
        f32x4 z1a = MFMA(xa0, W1B[0][0], c1zq);                                \
        f32x4 r1a = MFMA(xa0, W1B[1][0], c1rq);                                \
        f32x4 xh1 = MFMA(xa0, W1B[2][0], b1ihq);                               \
        z1a = MFMA(xa1, W1B[0][1], z1a);                                       \
        r1a = MFMA(xa1, W1B[1][1], r1a);                                       \
        xh1 = MFMA(xa1, W1B[2][1], xh1);                                       \
        /* U1-part chains (separate accumulators, 4-deep) */                   \
        f32x4 z1b = MFMA(A1[0], U1B[0][0], zeroq);                             \
        f32x4 r1b = MFMA(A1[0], U1B[1][0], zeroq);                             \
        f32x4 rh1 = MFMA(A1[0], U1B[2][0], b1rhq);                             \
        _Pragma("unroll") for (int kt = 1; kt < 4; kt++) {                     \
            z1b = MFMA(A1[kt], U1B[0][kt], z1b);                               \
            r1b = MFMA(A1[kt], U1B[1][kt], r1b);                               \
            rh1 = MFMA(A1[kt], U1B[2][kt], rh1);                               \
        }                                                                      \
        if ((T) > 0 && wave == 0) { /* publish h1(T-1): A-frag layout */       \
            _Pragma("unroll") for (int kt = 0; kt < 4; kt++)                   \
                *(bf16x8*)(h1f + ((size_t)((T) - 1) * 4 + kt) * 1024           \
                           + lane * 16) = A1[kt];                              \
        }                                                                      \
        f32x4 z1 = z1a + z1b;                                                  \
        f32x4 r1 = r1a + r1b;                                                  \
        _Pragma("unroll") for (int i = 0; i < 4; i++) {                        \
            float zf = sigf(z1[i]);                                            \
            float rf = sigf(r1[i]);                                            \
            float hh = fmaxf(xh1[i] + rf * rh1[i], 0.f);                       \
            h1c[i] = fmaf(zf, h1c[i] - hh, hh);                                \
            hs[PAR][quad * 4 + i][u] = (__bf16)h1c[i];                         \
        }                                                                      \
        if (wave == 0 && (T) > 0 && (((T) & 63) == 0)) {                       \
            __threadfence();                                                   \
            if (lane == 0)                                                     \
                __hip_atomic_store(flags + ((T) >> 6) - 1, 1u,                 \
                                   __ATOMIC_RELEASE,                           \
                                   __HIP_MEMORY_SCOPE_AGENT);                  \
        }                                                                      \
        asm volatile("s_waitcnt lgkmcnt(0)\n\ts_barrier" ::: "memory");        \
    }

        for (int t = 0; t < TT; t += 2) {
            PSTEP(t, 0)
            PSTEP(t + 1, 1)
        }
#undef PSTEP

        // epilogue: publish h1(1023) (lives in hs[1]) + final flag
        if (wave == 0) {
#pragma unroll
            for (int kt = 0; kt < 4; kt++) {
                bf16x8 a = *(const bf16x8*)&hs[1][lc][kt * 32 + quad * 8];
                *(bf16x8*)(h1f + ((size_t)(TT - 1) * 4 + kt) * 1024
                           + lane * 16) = a;
            }
            __threadfence();
            if (lane == 0)
                __hip_atomic_store(flags + NCH - 1, 1u, __ATOMIC_RELEASE,
                                   __HIP_MEMORY_SCOPE_AGENT);
        }
        // state1 = h1(1023)
#pragma unroll
        for (int i = 0; i < 4; i++) {
            int r = row0 + quad * 4 + i;
            out[32768 + (size_t)r * 128 + u] = h1c[i];
        }
    } else {
        // =================== CONSUMER: layer 2 ===========================
        bf16x8 W2B[3][4], U2B[3][4];      // 24 frags = 96 regs
#pragma unroll
        for (int g = 0; g < 3; g++)
#pragma unroll
            for (int kt = 0; kt < 4; kt++) {
                bf16x8 b, c;
#pragma unroll
                for (int j = 0; j < 8; j++) {
                    int k = (kt * 32 + quad * 8 + j) * G3 + g * 128 + u;
                    b[j] = (__bf16)W2[k];
                    c[j] = (__bf16)U2[k];
                }
                W2B[g][kt] = b;
                U2B[g][kt] = c;
            }
        const float c2z  = b2[u] + b2[G3 + u];
        const float c2r  = b2[128 + u] + b2[G3 + 128 + u];
        const float b2ih = b2[256 + u];
        const float b2rh = b2[G3 + 256 + u];
        const f32x4 c2zq  = {c2z, c2z, c2z, c2z};
        const f32x4 c2rq  = {c2r, c2r, c2r, c2r};
        const f32x4 b2ihq = {b2ih, b2ih, b2ih, b2ih};
        const f32x4 b2rhq = {b2rh, b2rh, b2rh, b2rh};

        float h2c[4] = {0, 0, 0, 0};
        bf16x8 hAa0, hAa1, hAa2, hAa3, hAb0, hAb1, hAb2, hAb3;
        __syncthreads();

// Uses C0..C3 (holds h1(T)); prefetches h1(T+2) back into C0..C3 after the
// W2-part MFMAs have consumed them (2-step distance, 2 buffers).
#define CSTEP(T, PAR, C0, C1, C2, C3)                                          \
    {                                                                          \
        bf16x8 A2[4];                                                          \
        _Pragma("unroll") for (int kt = 0; kt < 4; kt++)                       \
            A2[kt] = *(const bf16x8*)&hs[PAR ^ 1][lc][kt * 32 + quad * 8];     \
        /* W2-part chains (independent of A2 -> hide ds latency) */            \
        f32x4 z2a = MFMA(C0, W2B[0][0], c2zq);                                 \
        f32x4 r2a = MFMA(C0, W2B[1][0], c2rq);                                 \
        f32x4 xh2 = MFMA(C0, W2B[2][0], b2ihq);                                \
        z2a = MFMA(C1, W2B[0][1], z2a);                                        \
        r2a = MFMA(C1, W2B[1][1], r2a);                                        \
        xh2 = MFMA(C1, W2B[2][1], xh2);                                        \
        z2a = MFMA(C2, W2B[0][2], z2a);                                        \
        r2a = MFMA(C2, W2B[1][2], r2a);                                        \
        xh2 = MFMA(C2, W2B[2][2], xh2);                                        \
        z2a = MFMA(C3, W2B[0][3], z2a);                                        \
        r2a = MFMA(C3, W2B[1][3], r2a);                                        \
        xh2 = MFMA(C3, W2B[2][3], xh2);                                        \
        if ((T) + 2 < tend) { /* prefetch h1(T+2) into the freed buffer */     \
            const unsigned char* sp =                                          \
                h1f + (size_t)((T) + 2) * 4096 + lane * 16;                    \
            C0 = *(const bf16x8*)(sp);                                         \
            C1 = *(const bf16x8*)(sp + 1024);                                  \
            C2 = *(const bf16x8*)(sp + 2048);                                  \
            C3 = *(const bf16x8*)(sp + 3072);                                  \
        }                                                                      \
        /* U2-part chains (separate accumulators, 4-deep) */                   \
        f32x4 z2b = MFMA(A2[0], U2B[0][0], zeroq);                             \
        f32x4 r2b = MFMA(A2[0], U2B[1][0], zeroq);                             \
        f32x4 rh2 = MFMA(A2[0], U2B[2][0], b2rhq);                             \
        _Pragma("unroll") for (int kt = 1; kt < 4; kt++) {                     \
            z2b = MFMA(A2[kt], U2B[0][kt], z2b);                               \
            r2b = MFMA(A2[kt], U2B[1][kt], r2b);                               \
            rh2 = MFMA(A2[kt], U2B[2][kt], rh2);                               \
        }                                                                      \
        f32x4 z2 = z2a + z2b;                                                  \
        f32x4 r2 = r2a + r2b;                                                  \
        _Pragma("unroll") for (int i = 0; i < 4; i++) {                        \
            float zf = sigf(z2[i]);                                            \
            float rf = sigf(r2[i]);                                            \
            float hh = fmaxf(xh2[i] + rf * rh2[i], 0.f);                       \
            h2c[i] = fmaf(zf, h2c[i] - hh, hh);                                \
            hs[PAR][quad * 4 + i][u] = (__bf16)h2c[i];                         \
        }                                                                      \
        asm volatile("s_waitcnt lgkmcnt(0)\n\ts_barrier" ::: "memory");        \
    }

        for (int c = 0; c < NCH; c++) {
            wait_flag(flags + c);
            const int t0   = c * CHUNK;
            const int tend = t0 + CHUNK;
            {   // blocking load of h1(t0) and h1(t0+1)
                const unsigned char* sp = h1f + (size_t)t0 * 4096 + lane * 16;
                hAa0 = *(const bf16x8*)(sp);
                hAa1 = *(const bf16x8*)(sp + 1024);
                hAa2 = *(const bf16x8*)(sp + 2048);
                hAa3 = *(const bf16x8*)(sp + 3072);
                const unsigned char* sq = sp + 4096;
                hAb0 = *(const bf16x8*)(sq);
                hAb1 = *(const bf16x8*)(sq + 1024);
                hAb2 = *(const bf16x8*)(sq + 2048);
                hAb3 = *(const bf16x8*)(sq + 3072);
            }
            for (int t = t0; t < tend; t += 2) {
                CSTEP(t, 0, hAa0, hAa1, hAa2, hAa3)
                CSTEP(t + 1, 1, hAb0, hAb1, hAb2, hAb3)
            }
        }
#undef CSTEP

        // out: x = h2(1023), state2 = h2(1023)
#pragma unroll
        for (int i = 0; i < 4; i++) {
            int r = row0 + quad * 4 + i;
            out[(size_t)r * 128 + u]         = h2c[i];
            out[65536 + (size_t)r * 128 + u] = h2c[i];
        }
    }
}

// ---- monolithic fallback (ws too small): R13 gru_mono, proven correct -----
__global__ __launch_bounds__(512)
__attribute__((amdgpu_waves_per_eu(2, 2)))
void gru_mono(
    const float* __restrict__ x,  const float* __restrict__ W1,
    const float* __restrict__ U1, const float* __restrict__ b1,
    const float* __restrict__ W2, const float* __restrict__ U2,
    const float* __restrict__ b2, float* __restrict__ out)
{
    const int tid  = threadIdx.x;
    const int wave = tid >> 6;
    const int lane = tid & 63;
    const int quad = lane >> 4;
    const int lc   = lane & 15;
    const int row0 = blockIdx.x * 16;
    const int u    = wave * 16 + lc;

    __shared__ __align__(16) __bf16 h1s[2][16][136];
    __shared__ __align__(16) __bf16 h2s[2][16][136];
    for (int i = tid; i < 2 * 16 * 136; i += 512) {
        ((__bf16*)h1s)[i] = (__bf16)0.f;
        ((__bf16*)h2s)[i] = (__bf16)0.f;
    }

    bf16x8 U1B[3][4], W2B[3][4], U2B[3][4], W1B[3][2];
#pragma unroll
    for (int g = 0; g < 3; g++) {
#pragma unroll
        for (int kt = 0; kt < 4; kt++) {
            bf16x8 a, b, c;
#pragma unroll
            for (int j = 0; j < 8; j++) {
                int k = (kt * 32 + quad * 8 + j) * G3 + g * 128 + u;
                a[j] = (__bf16)U1[k];
                b[j] = (__bf16)W2[k];
                c[j] = (__bf16)U2[k];
            }
            U1B[g][kt] = a; W2B[g][kt] = b; U2B[g][kt] = c;
        }
#pragma unroll
        for (int kt = 0; kt < 2; kt++) {
            bf16x8 a;
#pragma unroll
            for (int j = 0; j < 8; j++)
                a[j] = (__bf16)W1[(kt * 32 + quad * 8 + j) * G3 + g * 128 + u];
            W1B[g][kt] = a;
        }
    }

    const float c1z  = b1[u] + b1[G3 + u];
    const float c1r  = b1[128 + u] + b1[G3 + 128 + u];
    const float b1ih = b1[256 + u];
    const float b1rh = b1[G3 + 256 + u];
    const float c2z  = b2[u] + b2[G3 + u];
    const float c2r  = b2[128 + u] + b2[G3 + 128 + u];
    const float b2ih = b2[256 + u];
    const float b2rh = b2[G3 + 256 + u];
    const f32x4 c1zq  = {c1z, c1z, c1z, c1z};
    const f32x4 c1rq  = {c1r, c1r, c1r, c1r};
    const f32x4 b1ihq = {b1ih, b1ih, b1ih, b1ih};
    const f32x4 b1rhq = {b1rh, b1rh, b1rh, b1rh};
    const f32x4 c2zq  = {c2z, c2z, c2z, c2z};
    const f32x4 c2rq  = {c2r, c2r, c2r, c2r};
    const f32x4 b2ihq = {b2ih, b2ih, b2ih, b2ih};
    const f32x4 b2rhq = {b2rh, b2rh, b2rh, b2rh};

    const float* xrow = x + (size_t)(row0 + lc) * (TT * FF) + quad * 8;
    float h1c[4] = {0, 0, 0, 0};
    float h2c[4] = {0, 0, 0, 0};
    __syncthreads();

#define MSTEP(T, PAR)                                                          \
    {                                                                          \
        bf16x8 A1[4];                                                          \
        _Pragma("unroll") for (int kt = 0; kt < 4; kt++)                       \
            A1[kt] = *(const bf16x8*)&h1s[PAR ^ 1][lc][kt * 32 + quad * 8];    \
        const float* px = xrow + (size_t)(T) * FF;                             \
        f32x4 u0 = *(const f32x4*)px;                                          \
        f32x4 u1 = *(const f32x4*)(px + 4);                                    \
        f32x4 u2 = *(const f32x4*)(px + 32);                                   \
        f32x4 u3 = *(const f32x4*)(px + 36);                                   \
        bf16x8 xa0, xa1;                                                       \
        _Pragma("unroll") for (int j = 0; j < 4; j++) {                        \
            xa0[j] = (__bf16)u0[j]; xa0[j + 4] = (__bf16)u1[j];                \
            xa1[j] = (__bf16)u2[j]; xa1[j + 4] = (__bf16)u3[j];                \
        }                                                                      \
        f32x4 z1  = MFMA(xa0, W1B[0][0], c1zq);                                \
        z1        = MFMA(xa1, W1B[0][1], z1);                                  \
        f32x4 r1  = MFMA(xa0, W1B[1][0], c1rq);                                \
        r1        = MFMA(xa1, W1B[1][1], r1);                                  \
        f32x4 xh1 = MFMA(xa0, W1B[2][0], b1ihq);                               \
        xh1       = MFMA(xa1, W1B[2][1], xh1);                                 \
        f32x4 rh1 = MFMA(A1[0], U1B[2][0], b1rhq);                             \
        z1        = MFMA(A1[0], U1B[0][0], z1);                                \
        r1        = MFMA(A1[0], U1B[1][0], r1);                                \
        _Pragma("unroll") for (int kt = 1; kt < 4; kt++) {                     \
            z1  = MFMA(A1[kt], U1B[0][kt], z1);                                \
            r1  = MFMA(A1[kt], U1B[1][kt], r1);                                \
            rh1 = MFMA(A1[kt], U1B[2][kt], rh1);                               \
        }                                                                      \
        _Pragma("unroll") for (int i = 0; i < 4; i++) {                        \
            float zf = sigf(z1[i]);                                            \
            float rf = sigf(r1[i]);                                            \
            float hh = fmaxf(xh1[i] + rf * rh1[i], 0.f);                       \
            h1c[i] = fmaf(zf, h1c[i] - hh, hh);                                \
            h1s[PAR][quad * 4 + i][u] = (__bf16)h1c[i];                        \
        }                                                                      \
        f32x4 z2  = MFMA(A1[0], W2B[0][0], c2zq);                              \
        f32x4 r2  = MFMA(A1[0], W2B[1][0], c2rq);                              \
        f32x4 xh2 = MFMA(A1[0], W2B[2][0], b2ihq);                             \
        _Pragma("unroll") for (int kt = 1; kt < 4; kt++) {                     \
            z2  = MFMA(A1[kt], W2B[0][kt], z2);                                \
            r2  = MFMA(A1[kt], W2B[1][kt], r2);                                \
            xh2 = MFMA(A1[kt], W2B[2][kt], xh2);                               \
        }                                                                      \
        f32x4 rh2;                                                             \
        {                                                                      \
            bf16x8 A2 = *(const bf16x8*)&h2s[PAR][lc][quad * 8];               \
            rh2 = MFMA(A2, U2B[2][0], b2rhq);                                  \
            z2  = MFMA(A2, U2B[0][0], z2);                                     \
            r2  = MFMA(A2, U2B[1][0], r2);                                     \
        }                                                                      \
        _Pragma("unroll") for (int kt = 1; kt < 4; kt++) {                     \
            bf16x8 A2 = *(const bf16x8*)&h2s[PAR][lc][kt * 32 + quad * 8];     \
            z2  = MFMA(A2, U2B[0][kt], z2);                                    \
            r2  = MFMA(A2, U2B[1][kt], r2);                                    \
            rh2 = MFMA(A2, U2B[2][kt], rh2);                                   \
        }                                                                      \
        if ((T) > 0) {                                                         \
            _Pragma("unroll") for (int i = 0; i < 4; i++) {                    \
                float zf = sigf(z2[i]);                                        \
                float rf = sigf(r2[i]);                                        \
                float hh = fmaxf(xh2[i] + rf * rh2[i], 0.f);                   \
                h2c[i] = fmaf(zf, h2c[i] - hh, hh);                            \
            }                                                                  \
        }                                                                      \
        _Pragma("unroll") for (int i = 0; i < 4; i++)                          \
            h2s[PAR ^ 1][quad * 4 + i][u] = (__bf16)h2c[i];                    \
        asm volatile("s_waitcnt lgkmcnt(0)\n\ts_barrier" ::: "memory");        \
    }

    for (int t = 0; t < TT; t += 2) {
        MSTEP(t, 0)
        MSTEP(t + 1, 1)
    }
#undef MSTEP

    {
        f32x4 z2 = c2zq, r2 = c2rq, xh2 = b2ihq, rh2 = b2rhq;
#pragma unroll
        for (int kt = 0; kt < 4; kt++) {
            bf16x8 a1 = *(const bf16x8*)&h1s[1][lc][kt * 32 + quad * 8];
            bf16x8 a2 = *(const bf16x8*)&h2s[0][lc][kt * 32 + quad * 8];
            z2  = MFMA(a1, W2B[0][kt], z2);
            r2  = MFMA(a1, W2B[1][kt], r2);
            xh2 = MFMA(a1, W2B[2][kt], xh2);
            z2  = MFMA(a2, U2B[0][kt], z2);
            r2  = MFMA(a2, U2B[1][kt], r2);
            rh2 = MFMA(a2, U2B[2][kt], rh2);
        }
#pragma unroll
        for (int i = 0; i < 4; i++) {
            float zf = sigf(z2[i]);
            float rf = sigf(r2[i]);
            float hh = fmaxf(xh2[i] + rf * rh2[i], 0.f);
            h2c[i] = fmaf(zf, h2c[i] - hh, hh);
        }
    }

#pragma unroll
    for (int i = 0; i < 4; i++) {
        int r = row0 + quad * 4 + i;
        out[(size_t)r * 128 + u]         = h2c[i];
        out[32768 + (size_t)r * 128 + u] = h1c[i];
        out[65536 + (size_t)r * 128 + u] = h2c[i];
    }
}

extern "C" void kernel_launch(void* const* d_in, const int* in_sizes, int n_in,
                              void* d_out, int out_size, void* d_ws, size_t ws_size,
                              hipStream_t stream) {
    const float* x  = (const float*)d_in[0];
    const float* W1 = (const float*)d_in[1];
    const float* U1 = (const float*)d_in[2];
    const float* b1 = (const float*)d_in[3];
    const float* W2 = (const float*)d_in[4];
    const float* U2 = (const float*)d_in[5];
    const float* b2 = (const float*)d_in[6];
    float* out = (float*)d_out;

    if (ws_size >= PIPE_WS) {
        hipMemsetAsync(d_ws, 0, FLAG_BYTES, stream);
        gru_pipe2<<<dim3(2 * NB), dim3(512), 0, stream>>>(
            x, W1, U1, b1, W2, U2, b2, (unsigned char*)d_ws, out);
    } else {
        gru_mono<<<dim3(NB), dim3(512), 0, stream>>>(
            x, W1, U1, b1, W2, U2, b2, out);
    }
}

// Round 10
// 1068.639 us; speedup vs baseline: 3.2221x; 1.0110x over previous
//
#include <hip/hip_runtime.h>

// Fused 2-layer GRU scan. B=256,T=1024,F=64,U=128.
// R17: skeleton shaving on the R16 pipeline (1080us). R15/R16 established
// the step is ~2.3-2.4k cyc nearly invariant to MFMA work (halving work:
// -1%; ILP 8->4: -3.5%) -- a per-step skeleton of barrier + LDS burst +
// trans latency + ~39% stall dominates. This round attacks its measurable
// parts: (1) LDS pad [16][136]->[16][140]: 272B row stride = bank stride 4
// = 2-way aliasing on b128 A-frag reads (SQ_LDS_BANK_CONFLICT 4.19M =
// ~128 cyc/CU/step); 280B = bank stride 6 = 16 distinct banks. (2) split
// the four 4-deep gate MFMA chains into 2+2 partials (+16 VGPR, ~21 cyc
// per dependent MFMA per R16's measured delta). (3) CHUNK 64->32: total =
// (1024 + CHUNK) x step, tail save ~30us for a cheap 1-wave fence per 32.
// Protocol, layout, roles: R16 verbatim otherwise.

#define TT 1024
#define FF 64
#define G3 384
#define NB 16
#define CHUNK 32
#define NCH (TT / CHUNK)
#define FLAG_BYTES ((size_t)NB * NCH * 4)
#define H1F_BYTES ((size_t)NB * TT * 4096)
#define PIPE_WS (FLAG_BYTES + H1F_BYTES)

typedef __attribute__((ext_vector_type(8))) __bf16 bf16x8;
typedef __attribute__((ext_vector_type(4))) float f32x4;

#define MFMA(a, b, c) __builtin_amdgcn_mfma_f32_16x16x32_bf16((a), (b), (c), 0, 0, 0)

__device__ __forceinline__ float sigf(float x) {
    return __builtin_amdgcn_rcpf(1.0f + __expf(-x));
}

__device__ __forceinline__ void wait_flag(const unsigned int* f) {
    while (__hip_atomic_load(f, __ATOMIC_ACQUIRE, __HIP_MEMORY_SCOPE_AGENT) == 0u)
        __builtin_amdgcn_s_sleep(1);
}

// ---- fused pipeline: blocks 0-15 layer1 producers, 16-31 layer2 consumers -
__global__ __launch_bounds__(512)
__attribute__((amdgpu_waves_per_eu(2, 2)))
void gru_pipe2(
    const float* __restrict__ x,  const float* __restrict__ W1,
    const float* __restrict__ U1, const float* __restrict__ b1,
    const float* __restrict__ W2, const float* __restrict__ U2,
    const float* __restrict__ b2, unsigned char* __restrict__ ws,
    float* __restrict__ out)
{
    const int tid  = threadIdx.x;
    const int wave = tid >> 6;
    const int lane = tid & 63;
    const int quad = lane >> 4;
    const int lc   = lane & 15;
    const int rb   = blockIdx.x & 15;
    const int row0 = rb * 16;
    const int u    = wave * 16 + lc;

    unsigned int* flags = (unsigned int*)ws + rb * NCH;
    unsigned char* h1f  = ws + FLAG_BYTES + (size_t)rb * TT * 4096;

    // 140-col pad: 280B row stride -> bank stride 6 -> 16 distinct banks
    __shared__ __align__(16) __bf16 hs[2][16][140];
    for (int i = tid; i < 2 * 16 * 140; i += 512)
        ((__bf16*)hs)[i] = (__bf16)0.f;

    const f32x4 zeroq = {0.f, 0.f, 0.f, 0.f};

    if (blockIdx.x < NB) {
        // =================== PRODUCER: layer 1 ===========================
        bf16x8 U1B[3][4], W1B[3][2];      // 18 frags = 72 regs
#pragma unroll
        for (int g = 0; g < 3; g++) {
#pragma unroll
            for (int kt = 0; kt < 4; kt++) {
                bf16x8 a;
#pragma unroll
                for (int j = 0; j < 8; j++)
                    a[j] = (__bf16)U1[(kt * 32 + quad * 8 + j) * G3 + g * 128 + u];
                U1B[g][kt] = a;
            }
#pragma unroll
            for (int kt = 0; kt < 2; kt++) {
                bf16x8 a;
#pragma unroll
                for (int j = 0; j < 8; j++)
                    a[j] = (__bf16)W1[(kt * 32 + quad * 8 + j) * G3 + g * 128 + u];
                W1B[g][kt] = a;
            }
        }
        const float c1z  = b1[u] + b1[G3 + u];
        const float c1r  = b1[128 + u] + b1[G3 + 128 + u];
        const float b1ih = b1[256 + u];
        const float b1rh = b1[G3 + 256 + u];
        const f32x4 c1zq  = {c1z, c1z, c1z, c1z};
        const f32x4 c1rq  = {c1r, c1r, c1r, c1r};
        const f32x4 b1ihq = {b1ih, b1ih, b1ih, b1ih};
        const f32x4 b1rhq = {b1rh, b1rh, b1rh, b1rh};

        const float* xrow = x + (size_t)(row0 + lc) * (TT * FF) + quad * 8;
        f32x4 xp0 = *(const f32x4*)(xrow);
        f32x4 xp1 = *(const f32x4*)(xrow + 4);
        f32x4 xp2 = *(const f32x4*)(xrow + 32);
        f32x4 xp3 = *(const f32x4*)(xrow + 36);

        float h1c[4] = {0, 0, 0, 0};
        __syncthreads();

#define PSTEP(T, PAR)                                                          \
    {                                                                          \
        bf16x8 A1[4];                                                          \
        _Pragma("unroll") for (int kt = 0; kt < 4; kt++)                       \
            A1[kt] = *(const bf16x8*)&hs[PAR ^ 1][lc][kt * 32 + quad * 8];     \
        bf16x8 xa0, xa1;                                                       \
        _Pragma("unroll") for (int j = 0; j < 4; j++) {                        \
            xa0[j] = (__bf16)xp0[j]; xa0[j + 4] = (__bf16)xp1[j];              \
            xa1[j] = (__bf16)xp2[j]; xa1[j + 4] = (__bf16)xp3[j];              \
        }                                                                      \
        if ((T) + 1 < TT) {                                                    \
            const float* px = xrow + (size_t)((T) + 1) * FF;                   \
            xp0 = *(const f32x4*)px;                                           \
            xp1 = *(const f32x4*)(px + 4);                                     \
            xp2 = *(const f32x4*)(px + 32);                                    \
            xp3 = *(const f32x4*)(px + 36);                                    \
        }                                                                      \
        /* W1-part chains (independent of A1 -> hide ds latency) */            \
        f32x4 z1a = MFMA(xa0, W1B[0][0], c1zq);                                \
        f32x4 r1a = MFMA(xa0, W1B[1][0], c1rq);                                \
        f32x4 xh1 = MFMA(xa0, W1B[2][0], b1ihq);                               \
        z1a = MFMA(xa1, W1B[0][1], z1a);                                       \
        r1a = MFMA(xa1, W1B[1][1], r1a);                                       \
        xh1 = MFMA(xa1, W1B[2][1], xh1);                                       \
        /* U1-part: two depth-2 chains per gate */                             \
        f32x4 z1b = MFMA(A1[0], U1B[0][0], zeroq);                             \
        f32x4 r1b = MFMA(A1[0], U1B[1][0], zeroq);                             \
        f32x4 rh1 = MFMA(A1[0], U1B[2][0], b1rhq);                             \
        f32x4 z1d = MFMA(A1[1], U1B[0][1], zeroq);                             \
        f32x4 r1d = MFMA(A1[1], U1B[1][1], zeroq);                             \
        rh1 = MFMA(A1[1], U1B[2][1], rh1);                                     \
        z1b = MFMA(A1[2], U1B[0][2], z1b);                                     \
        r1b = MFMA(A1[2], U1B[1][2], r1b);                                     \
        rh1 = MFMA(A1[2], U1B[2][2], rh1);                                     \
        z1d = MFMA(A1[3], U1B[0][3], z1d);                                     \
        r1d = MFMA(A1[3], U1B[1][3], r1d);                                     \
        rh1 = MFMA(A1[3], U1B[2][3], rh1);                                     \
        if ((T) > 0 && wave == 0) { /* publish h1(T-1): A-frag layout */       \
            _Pragma("unroll") for (int kt = 0; kt < 4; kt++)                   \
                *(bf16x8*)(h1f + ((size_t)((T) - 1) * 4 + kt) * 1024           \
                           + lane * 16) = A1[kt];                              \
        }                                                                      \
        f32x4 z1 = z1a + (z1b + z1d);                                          \
        f32x4 r1 = r1a + (r1b + r1d);                                          \
        _Pragma("unroll") for (int i = 0; i < 4; i++) {                        \
            float zf = sigf(z1[i]);                                            \
            float rf = sigf(r1[i]);                                            \
            float hh = fmaxf(xh1[i] + rf * rh1[i], 0.f);                       \
            h1c[i] = fmaf(zf, h1c[i] - hh, hh);                                \
            hs[PAR][quad * 4 + i][u] = (__bf16)h1c[i];                         \
        }                                                                      \
        if (wave == 0 && (T) > 0 && (((T) & (CHUNK - 1)) == 0)) {              \
            __threadfence();                                                   \
            if (lane == 0)                                                     \
                __hip_atomic_store(flags + ((T) / CHUNK) - 1, 1u,              \
                                   __ATOMIC_RELEASE,                           \
                                   __HIP_MEMORY_SCOPE_AGENT);                  \
        }                                                                      \
        asm volatile("s_waitcnt lgkmcnt(0)\n\ts_barrier" ::: "memory");        \
    }

        for (int t = 0; t < TT; t += 2) {
            PSTEP(t, 0)
            PSTEP(t + 1, 1)
        }
#undef PSTEP

        // epilogue: publish h1(1023) (lives in hs[1]) + final flag
        if (wave == 0) {
#pragma unroll
            for (int kt = 0; kt < 4; kt++) {
                bf16x8 a = *(const bf16x8*)&hs[1][lc][kt * 32 + quad * 8];
                *(bf16x8*)(h1f + ((size_t)(TT - 1) * 4 + kt) * 1024
                           + lane * 16) = a;
            }
            __threadfence();
            if (lane == 0)
                __hip_atomic_store(flags + NCH - 1, 1u, __ATOMIC_RELEASE,
                                   __HIP_MEMORY_SCOPE_AGENT);
        }
        // state1 = h1(1023)
#pragma unroll
        for (int i = 0; i < 4; i++) {
            int r = row0 + quad * 4 + i;
            out[32768 + (size_t)r * 128 + u] = h1c[i];
        }
    } else {
        // =================== CONSUMER: layer 2 ===========================
        bf16x8 W2B[3][4], U2B[3][4];      // 24 frags = 96 regs
#pragma unroll
        for (int g = 0; g < 3; g++)
#pragma unroll
            for (int kt = 0; kt < 4; kt++) {
                bf16x8 b, c;
#pragma unroll
                for (int j = 0; j < 8; j++) {
                    int k = (kt * 32 + quad * 8 + j) * G3 + g * 128 + u;
                    b[j] = (__bf16)W2[k];
                    c[j] = (__bf16)U2[k];
                }
                W2B[g][kt] = b;
                U2B[g][kt] = c;
            }
        const float c2z  = b2[u] + b2[G3 + u];
        const float c2r  = b2[128 + u] + b2[G3 + 128 + u];
        const float b2ih = b2[256 + u];
        const float b2rh = b2[G3 + 256 + u];
        const f32x4 c2zq  = {c2z, c2z, c2z, c2z};
        const f32x4 c2rq  = {c2r, c2r, c2r, c2r};
        const f32x4 b2ihq = {b2ih, b2ih, b2ih, b2ih};
        const f32x4 b2rhq = {b2rh, b2rh, b2rh, b2rh};

        float h2c[4] = {0, 0, 0, 0};
        bf16x8 hAa0, hAa1, hAa2, hAa3, hAb0, hAb1, hAb2, hAb3;
        __syncthreads();

// Uses C0..C3 (holds h1(T)); prefetches h1(T+2) back into C0..C3 after the
// W2-part MFMAs have consumed them (2-step distance, 2 buffers).
#define CSTEP(T, PAR, C0, C1, C2, C3)                                          \
    {                                                                          \
        bf16x8 A2[4];                                                          \
        _Pragma("unroll") for (int kt = 0; kt < 4; kt++)                       \
            A2[kt] = *(const bf16x8*)&hs[PAR ^ 1][lc][kt * 32 + quad * 8];     \
        /* W2-part: two depth-2 chains per gate (fill ds window) */            \
        f32x4 z2a = MFMA(C0, W2B[0][0], c2zq);                                 \
        f32x4 r2a = MFMA(C0, W2B[1][0], c2rq);                                 \
        f32x4 xh2 = MFMA(C0, W2B[2][0], b2ihq);                                \
        f32x4 z2c = MFMA(C1, W2B[0][1], zeroq);                                \
        f32x4 r2c = MFMA(C1, W2B[1][1], zeroq);                                \
        xh2 = MFMA(C1, W2B[2][1], xh2);                                        \
        z2a = MFMA(C2, W2B[0][2], z2a);                                        \
        r2a = MFMA(C2, W2B[1][2], r2a);                                        \
        xh2 = MFMA(C2, W2B[2][2], xh2);                                        \
        z2c = MFMA(C3, W2B[0][3], z2c);                                        \
        r2c = MFMA(C3, W2B[1][3], r2c);                                        \
        xh2 = MFMA(C3, W2B[2][3], xh2);                                        \
        if ((T) + 2 < tend) { /* prefetch h1(T+2) into the freed buffer */     \
            const unsigned char* sp =                                          \
                h1f + (size_t)((T) + 2) * 4096 + lane * 16;                    \
            C0 = *(const bf16x8*)(sp);                                         \
            C1 = *(const bf16x8*)(sp + 1024);                                  \
            C2 = *(const bf16x8*)(sp + 2048);                                  \
            C3 = *(const bf16x8*)(sp + 3072);                                  \
        }                                                                      \
        /* U2-part: two depth-2 chains per gate */                             \
        f32x4 z2b = MFMA(A2[0], U2B[0][0], zeroq);                             \
        f32x4 r2b = MFMA(A2[0], U2B[1][0], zeroq);                             \
        f32x4 rh2 = MFMA(A2[0], U2B[2][0], b2rhq);                             \
        f32x4 z2d = MFMA(A2[1], U2B[0][1], zeroq);                             \
        f32x4 r2d = MFMA(A2[1], U2B[1][1], zeroq);                             \
        rh2 = MFMA(A2[1], U2B[2][1], rh2);                                     \
        z2b = MFMA(A2[2], U2B[0][2], z2b);                                     \
        r2b = MFMA(A2[2], U2B[1][2], r2b);                                     \
        rh2 = MFMA(A2[2], U2B[2][2], rh2);                                     \
        z2d = MFMA(A2[3], U2B[0][3], z2d);                                     \
        r2d = MFMA(A2[3], U2B[1][3], r2d);                                     \
        rh2 = MFMA(A2[3], U2B[2][3], rh2);                                     \
        f32x4 z2 = (z2a + z2c) + (z2b + z2d);                                  \
        f32x4 r2 = (r2a + r2c) + (r2b + r2d);                                  \
        _Pragma("unroll") for (int i = 0; i < 4; i++) {                        \
            float zf = sigf(z2[i]);                                            \
            float rf = sigf(r2[i]);                                            \
            float hh = fmaxf(xh2[i] + rf * rh2[i], 0.f);                       \
            h2c[i] = fmaf(zf, h2c[i] - hh, hh);                                \
            hs[PAR][quad * 4 + i][u] = (__bf16)h2c[i];                         \
        }                                                                      \
        asm volatile("s_waitcnt lgkmcnt(0)\n\ts_barrier" ::: "memory");        \
    }

        for (int c = 0; c < NCH; c++) {
            wait_flag(flags + c);
            const int t0   = c * CHUNK;
            const int tend = t0 + CHUNK;
            {   // blocking load of h1(t0) and h1(t0+1)
                const unsigned char* sp = h1f + (size_t)t0 * 4096 + lane * 16;
                hAa0 = *(const bf16x8*)(sp);
                hAa1 = *(const bf16x8*)(sp + 1024);
                hAa2 = *(const bf16x8*)(sp + 2048);
                hAa3 = *(const bf16x8*)(sp + 3072);
                const unsigned char* sq = sp + 4096;
                hAb0 = *(const bf16x8*)(sq);
                hAb1 = *(const bf16x8*)(sq + 1024);
                hAb2 = *(const bf16x8*)(sq + 2048);
                hAb3 = *(const bf16x8*)(sq + 3072);
            }
            for (int t = t0; t < tend; t += 2) {
                CSTEP(t, 0, hAa0, hAa1, hAa2, hAa3)
                CSTEP(t + 1, 1, hAb0, hAb1, hAb2, hAb3)
            }
        }
#undef CSTEP

        // out: x = h2(1023), state2 = h2(1023)
#pragma unroll
        for (int i = 0; i < 4; i++) {
            int r = row0 + quad * 4 + i;
            out[(size_t)r * 128 + u]         = h2c[i];
            out[65536 + (size_t)r * 128 + u] = h2c[i];
        }
    }
}

// ---- monolithic fallback (ws too small): R13 gru_mono, proven correct -----
__global__ __launch_bounds__(512)
__attribute__((amdgpu_waves_per_eu(2, 2)))
void gru_mono(
    const float* __restrict__ x,  const float* __restrict__ W1,
    const float* __restrict__ U1, const float* __restrict__ b1,
    const float* __restrict__ W2, const float* __restrict__ U2,
    const float* __restrict__ b2, float* __restrict__ out)
{
    const int tid  = threadIdx.x;
    const int wave = tid >> 6;
    const int lane = tid & 63;
    const int quad = lane >> 4;
    const int lc   = lane & 15;
    const int row0 = blockIdx.x * 16;
    const int u    = wave * 16 + lc;

    __shared__ __align__(16) __bf16 h1s[2][16][136];
    __shared__ __align__(16) __bf16 h2s[2][16][136];
    for (int i = tid; i < 2 * 16 * 136; i += 512) {
        ((__bf16*)h1s)[i] = (__bf16)0.f;
        ((__bf16*)h2s)[i] = (__bf16)0.f;
    }

    bf16x8 U1B[3][4], W2B[3][4], U2B[3][4], W1B[3][2];
#pragma unroll
    for (int g = 0; g < 3; g++) {
#pragma unroll
        for (int kt = 0; kt < 4; kt++) {
            bf16x8 a, b, c;
#pragma unroll
            for (int j = 0; j < 8; j++) {
                int k = (kt * 32 + quad * 8 + j) * G3 + g * 128 + u;
                a[j] = (__bf16)U1[k];
                b[j] = (__bf16)W2[k];
                c[j] = (__bf16)U2[k];
            }
            U1B[g][kt] = a; W2B[g][kt] = b; U2B[g][kt] = c;
        }
#pragma unroll
        for (int kt = 0; kt < 2; kt++) {
            bf16x8 a;
#pragma unroll
            for (int j = 0; j < 8; j++)
                a[j] = (__bf16)W1[(kt * 32 + quad * 8 + j) * G3 + g * 128 + u];
            W1B[g][kt] = a;
        }
    }

    const float c1z  = b1[u] + b1[G3 + u];
    const float c1r  = b1[128 + u] + b1[G3 + 128 + u];
    const float b1ih = b1[256 + u];
    const float b1rh = b1[G3 + 256 + u];
    const float c2z  = b2[u] + b2[G3 + u];
    const float c2r  = b2[128 + u] + b2[G3 + 128 + u];
    const float b2ih = b2[256 + u];
    const float b2rh = b2[G3 + 256 + u];
    const f32x4 c1zq  = {c1z, c1z, c1z, c1z};
    const f32x4 c1rq  = {c1r, c1r, c1r, c1r};
    const f32x4 b1ihq = {b1ih, b1ih, b1ih, b1ih};
    const f32x4 b1rhq = {b1rh, b1rh, b1rh, b1rh};
    const f32x4 c2zq  = {c2z, c2z, c2z, c2z};
    const f32x4 c2rq  = {c2r, c2r, c2r, c2r};
    const f32x4 b2ihq = {b2ih, b2ih, b2ih, b2ih};
    const f32x4 b2rhq = {b2rh, b2rh, b2rh, b2rh};

    const float* xrow = x + (size_t)(row0 + lc) * (TT * FF) + quad * 8;
    float h1c[4] = {0, 0, 0, 0};
    float h2c[4] = {0, 0, 0, 0};
    __syncthreads();

#define MSTEP(T, PAR)                                                          \
    {                                                                          \
        bf16x8 A1[4];                                                          \
        _Pragma("unroll") for (int kt = 0; kt < 4; kt++)                       \
            A1[kt] = *(const bf16x8*)&h1s[PAR ^ 1][lc][kt * 32 + quad * 8];    \
        const float* px = xrow + (size_t)(T) * FF;                             \
        f32x4 u0 = *(const f32x4*)px;                                          \
        f32x4 u1 = *(const f32x4*)(px + 4);                                    \
        f32x4 u2 = *(const f32x4*)(px + 32);                                   \
        f32x4 u3 = *(const f32x4*)(px + 36);                                   \
        bf16x8 xa0, xa1;                                                       \
        _Pragma("unroll") for (int j = 0; j < 4; j++) {                        \
            xa0[j] = (__bf16)u0[j]; xa0[j + 4] = (__bf16)u1[j];                \
            xa1[j] = (__bf16)u2[j]; xa1[j + 4] = (__bf16)u3[j];                \
        }                                                                      \
        f32x4 z1  = MFMA(xa0, W1B[0][0], c1zq);                                \
        z1        = MFMA(xa1, W1B[0][1], z1);                                  \
        f32x4 r1  = MFMA(xa0, W1B[1][0], c1rq);                                \
        r1        = MFMA(xa1, W1B[1][1], r1);                                  \
        f32x4 xh1 = MFMA(xa0, W1B[2][0], b1ihq);                               \
        xh1       = MFMA(xa1, W1B[2][1], xh1);                                 \
        f32x4 rh1 = MFMA(A1[0], U1B[2][0], b1rhq);                             \
        z1        = MFMA(A1[0], U1B[0][0], z1);                                \
        r1        = MFMA(A1[0], U1B[1][0], r1);                                \
        _Pragma("unroll") for (int kt = 1; kt < 4; kt++) {                     \
            z1  = MFMA(A1[kt], U1B[0][kt], z1);                                \
            r1  = MFMA(A1[kt], U1B[1][kt], r1);                                \
            rh1 = MFMA(A1[kt], U1B[2][kt], rh1);                               \
        }                                                                      \
        _Pragma("unroll") for (int i = 0; i < 4; i++) {                        \
            float zf = sigf(z1[i]);                                            \
            float rf = sigf(r1[i]);                                            \
            float hh = fmaxf(xh1[i] + rf * rh1[i], 0.f);                       \
            h1c[i] = fmaf(zf, h1c[i] - hh, hh);                                \
            h1s[PAR][quad * 4 + i][u] = (__bf16)h1c[i];                        \
        }                                                                      \
        f32x4 z2  = MFMA(A1[0], W2B[0][0], c2zq);                              \
        f32x4 r2  = MFMA(A1[0], W2B[1][0], c2rq);                              \
        f32x4 xh2 = MFMA(A1[0], W2B[2][0], b2ihq);                             \
        _Pragma("unroll") for (int kt = 1; kt < 4; kt++) {                     \
            z2  = MFMA(A1[kt], W2B[0][kt], z2);                                \
            r2  = MFMA(A1[kt], W2B[1][kt], r2);                                \
            xh2 = MFMA(A1[kt], W2B[2][kt], xh2);                               \
        }                                                                      \
        f32x4 rh2;                                                             \
        {                                                                      \
            bf16x8 A2 = *(const bf16x8*)&h2s[PAR][lc][quad * 8];               \
            rh2 = MFMA(A2, U2B[2][0], b2rhq);                                  \
            z2  = MFMA(A2, U2B[0][0], z2);                                     \
            r2  = MFMA(A2, U2B[1][0], r2);                                     \
        }                                                                      \
        _Pragma("unroll") for (int kt = 1; kt < 4; kt++) {                     \
            bf16x8 A2 = *(const bf16x8*)&h2s[PAR][lc][kt * 32 + quad * 8];     \
            z2  = MFMA(A2, U2B[0][kt], z2);                                    \
            r2  = MFMA(A2, U2B[1][kt], r2);                                    \
            rh2 = MFMA(A2, U2B[2][kt], rh2);                                   \
        }                                                                      \
        if ((T) > 0) {                                                         \
            _Pragma("unroll") for (int i = 0; i < 4; i++) {                    \
                float zf = sigf(z2[i]);                                        \
                float rf = sigf(r2[i]);                                        \
                float hh = fmaxf(xh2[i] + rf * rh2[i], 0.f);                   \
                h2c[i] = fmaf(zf, h2c[i] - hh, hh);                            \
            }                                                                  \
        }                                                                      \
        _Pragma("unroll") for (int i = 0; i < 4; i++)                          \
            h2s[PAR ^ 1][quad * 4 + i][u] = (__bf16)h2c[i];                    \
        asm volatile("s_waitcnt lgkmcnt(0)\n\ts_barrier" ::: "memory");        \
    }

    for (int t = 0; t < TT; t += 2) {
        MSTEP(t, 0)
        MSTEP(t + 1, 1)
    }
#undef MSTEP

    {
        f32x4 z2 = c2zq, r2 = c2rq, xh2 = b2ihq, rh2 = b2rhq;
#pragma unroll
        for (int kt = 0; kt < 4; kt++) {
            bf16x8 a1 = *(const bf16x8*)&h1s[1][lc][kt * 32 + quad * 8];
            bf16x8 a2 = *(const bf16x8*)&h2s[0][lc][kt * 32 + quad * 8];
            z2  = MFMA(a1, W2B[0][kt], z2);
            r2  = MFMA(a1, W2B[1][kt], r2);
            xh2 = MFMA(a1, W2B[2][kt], xh2);
            z2  = MFMA(a2, U2B[0][kt], z2);
            r2  = MFMA(a2, U2B[1][kt], r2);
            rh2 = MFMA(a2, U2B[2][kt], rh2);
        }
#pragma unroll
        for (int i = 0; i < 4; i++) {
            float zf = sigf(z2[i]);
            float rf = sigf(r2[i]);
            float hh = fmaxf(xh2[i] + rf * rh2[i], 0.f);
            h2c[i] = fmaf(zf, h2c[i] - hh, hh);
        }
    }

#pragma unroll
    for (int i = 0; i < 4; i++) {
        int r = row0 + quad * 4 + i;
        out[(size_t)r * 128 + u]         = h2c[i];
        out[32768 + (size_t)r * 128 + u] = h1c[i];
        out[65536 + (size_t)r * 128 + u] = h2c[i];
    }
}

extern "C" void kernel_launch(void* const* d_in, const int* in_sizes, int n_in,
                              void* d_out, int out_size, void* d_ws, size_t ws_size,
                              hipStream_t stream) {
    const float* x  = (const float*)d_in[0];
    const float* W1 = (const float*)d_in[1];
    const float* U1 = (const float*)d_in[2];
    const float* b1 = (const float*)d_in[3];
    const float* W2 = (const float*)d_in[4];
    const float* U2 = (const float*)d_in[5];
    const float* b2 = (const float*)d_in[6];
    float* out = (float*)d_out;

    if (ws_size >= PIPE_WS) {
        hipMemsetAsync(d_ws, 0, FLAG_BYTES, stream);
        gru_pipe2<<<dim3(2 * NB), dim3(512), 0, stream>>>(
            x, W1, U1, b1, W2, U2, b2, (unsigned char*)d_ws, out);
    } else {
        gru_mono<<<dim3(NB), dim3(512), 0, stream>>>(
            x, W1, U1, b1, W2, U2, b2, out);
    }
}